// Round 17
// baseline (3590.133 us; speedup 1.0000x reference)
//
#include <hip/hip_runtime.h>
#include <hip/hip_bf16.h>
#include <math.h>

#define DEVFN __device__ __forceinline__

constexpr int B_ = 16, N_ = 512, K_ = 30, H_ = 128;
constexpr int NH_ = 4, V_ = 20;
constexpr int BN_ = B_ * N_;
constexpr float NEG_INF_ = -3.4028235e38f;

DEVFN float block_sum128f(float v, float* sbuf) {
  int t = threadIdx.x;
  sbuf[t] = v; __syncthreads();
  #pragma unroll
  for (int s = 64; s > 0; s >>= 1) {
    if (t < s) sbuf[t] += sbuf[t + s];
    __syncthreads();
  }
  float r = sbuf[0];
  __syncthreads();
  return r;
}

// ---------------- top-K neighbors: distances BIT-EXACT to plain numpy float32 ----------------
// DO NOT TOUCH the distance math / tie-break: bit-exact __f*_rn distance + higher-index
// tie-break matches the np reference at exact ties (bf16-valued coords) — R8 fix.
__global__ __launch_bounds__(256) void topk_kernel(const float* __restrict__ X,
    const float* __restrict__ mask, int* __restrict__ E_idx, float* __restrict__ Dnb) {
  __shared__ float xs[N_ * 3];
  __shared__ float ds[N_];
  __shared__ float fred[256];
  __shared__ unsigned long long kred[4];
  int b = blockIdx.x / N_, i = blockIdx.x % N_;
  int t = threadIdx.x;
  for (int j = t; j < N_; j += 256) {
    const float* p = X + ((size_t)(b * N_ + j) * 4 + 1) * 3;  // CA atom
    xs[j * 3 + 0] = p[0]; xs[j * 3 + 1] = p[1]; xs[j * 3 + 2] = p[2];
  }
  __syncthreads();
  float xi0 = xs[i * 3], xi1 = xs[i * 3 + 1], xi2 = xs[i * 3 + 2];
  float mi = mask[b * N_ + i];
  float lmax = -3.4e38f;
  for (int j = t; j < N_; j += 256) {
    float dx = __fsub_rn(xi0, xs[j * 3]);
    float dy = __fsub_rn(xi1, xs[j * 3 + 1]);
    float dz = __fsub_rn(xi2, xs[j * 3 + 2]);
    float m2 = __fmul_rn(mi, mask[b * N_ + j]);
    float s = __fadd_rn(__fadd_rn(__fadd_rn(__fmul_rn(dx, dx), __fmul_rn(dy, dy)),
                                  __fmul_rn(dz, dz)), 1e-6f);
    float D = __fmul_rn(m2, __fsqrt_rn(s));
    ds[j] = D;
    lmax = fmaxf(lmax, D);
  }
  fred[t] = lmax; __syncthreads();
  for (int s = 128; s > 0; s >>= 1) { if (t < s) fred[t] = fmaxf(fred[t], fred[t + s]); __syncthreads(); }
  float Dmax = fred[0]; __syncthreads();
  for (int j = t; j < N_; j += 256) {
    float m2 = __fmul_rn(mi, mask[b * N_ + j]);
    ds[j] = __fadd_rn(ds[j], __fmul_rn(__fsub_rn(1.f, m2), Dmax));
  }
  __syncthreads();
  // extract K smallest; equal distances -> HIGHER index first (key = dist || N-1-j)
  int lane = t & 63, wv = t >> 6;
  for (int kk = 0; kk < K_; kk++) {
    unsigned long long best = ~0ull;
    for (int j = t; j < N_; j += 256) {
      unsigned long long key = (((unsigned long long)__float_as_uint(ds[j])) << 32)
                             | (unsigned)(N_ - 1 - j);
      if (key < best) best = key;
    }
    #pragma unroll
    for (int off = 32; off > 0; off >>= 1) {
      unsigned long long o = __shfl_xor(best, off, 64);
      if (o < best) best = o;
    }
    if (lane == 0) kred[wv] = best;
    __syncthreads();
    if (t == 0) {
      unsigned long long k0 = kred[0];
      if (kred[1] < k0) k0 = kred[1];
      if (kred[2] < k0) k0 = kred[2];
      if (kred[3] < k0) k0 = kred[3];
      int j = N_ - 1 - (int)(k0 & 0xffffffffull);
      E_idx[blockIdx.x * K_ + kk] = j;
      Dnb[blockIdx.x * K_ + kk] = __uint_as_float((unsigned)(k0 >> 32));
      ds[j] = 3.4028235e38f;
    }
    __syncthreads();
  }
}

// ---------------- dihedral features (1 thread / node), fp32 ----------------
DEVFN void load_atom(const float* X, int b, int m, float* p) {
  const float* q = X + ((size_t)(b * N_ + m / 3) * 4 + (m % 3)) * 3;
  p[0] = q[0]; p[1] = q[1]; p[2] = q[2];
}
DEVFN void cross3(const float* a, const float* b, float* c) {
  c[0] = a[1] * b[2] - a[2] * b[1];
  c[1] = a[2] * b[0] - a[0] * b[2];
  c[2] = a[0] * b[1] - a[1] * b[0];
}
DEVFN void norm3(float* v) {
  float n = sqrtf(v[0] * v[0] + v[1] * v[1] + v[2] * v[2]) + 1e-7f;
  v[0] /= n; v[1] /= n; v[2] /= n;
}
__global__ __launch_bounds__(256) void dihedral_kernel(const float* __restrict__ X, float* __restrict__ Vf) {
  int idx = blockIdx.x * blockDim.x + threadIdx.x;
  if (idx >= BN_) return;
  int b = idx / N_, n = idx % N_;
  float cs[3], sn[3];
  for (int s = 0; s < 3; s++) {
    int p = 3 * n + s;
    float a = 0.f;
    if (p >= 1 && p <= 3 * N_ - 3) {
      int tt = p - 1;
      float u[3][3], prev[3], cur[3];
      load_atom(X, b, tt, prev);
      for (int q = 0; q < 3; q++) {
        load_atom(X, b, tt + q + 1, cur);
        float d0 = cur[0] - prev[0], d1 = cur[1] - prev[1], d2 = cur[2] - prev[2];
        float nr = sqrtf(d0 * d0 + d1 * d1 + d2 * d2) + 1e-7f;
        u[q][0] = d0 / nr; u[q][1] = d1 / nr; u[q][2] = d2 / nr;
        prev[0] = cur[0]; prev[1] = cur[1]; prev[2] = cur[2];
      }
      float n2v[3], n1v[3];
      cross3(u[0], u[1], n2v); norm3(n2v);
      cross3(u[1], u[2], n1v); norm3(n1v);
      float cd = n2v[0] * n1v[0] + n2v[1] * n1v[1] + n2v[2] * n1v[2];
      cd = fminf(fmaxf(cd, -1.f + 1e-7f), 1.f - 1e-7f);
      float dt = u[0][0] * n1v[0] + u[0][1] * n1v[1] + u[0][2] * n1v[2];
      float sg = (dt > 0.f) ? 1.f : ((dt < 0.f) ? -1.f : 0.f);
      a = sg * acosf(cd);
    }
    cs[s] = cosf(a); sn[s] = sinf(a);
  }
  float* o = Vf + (size_t)idx * 6;
  o[0] = cs[0]; o[1] = cs[1]; o[2] = cs[2]; o[3] = sn[0]; o[4] = sn[1]; o[5] = sn[2];
}

// ---------------- node embed: hV = LN(V@Wfn+bfn) @ Wv + bv (fp32) ----------------
__global__ __launch_bounds__(H_) void node_embed_kernel(const float* __restrict__ Vf,
    const float* __restrict__ Wfn, const float* __restrict__ bfn,
    const float* __restrict__ Wv, const float* __restrict__ bv, float* __restrict__ hV) {
  int node = blockIdx.x, t = threadIdx.x;
  __shared__ float v6[6];
  __shared__ float t1[H_];
  __shared__ float red[H_];
  if (t < 6) v6[t] = Vf[(size_t)node * 6 + t];
  __syncthreads();
  float acc = bfn[t];
  for (int f = 0; f < 6; f++) acc = fmaf(v6[f], Wfn[f * H_ + t], acc);
  float mean = block_sum128f(acc, red) * (1.f / H_);
  float d0 = acc - mean;
  float var = block_sum128f(d0 * d0, red) * (1.f / H_);
  t1[t] = d0 * rsqrtf(var + 1e-6f);
  __syncthreads();
  float o = bv[t];
  for (int j = 0; j < H_; j++) o = fmaf(t1[j], Wv[j * H_ + t], o);
  hV[(size_t)node * H_ + t] = o;
}

// ---------------- edge embed, EB=16 edges/block: hE = LN(E@Wfe+bfe) @ We + be ----------------
constexpr int EB_ = 16;
__global__ __launch_bounds__(H_) void edge_embed_kernel(const int* __restrict__ E_idx,
    const float* __restrict__ Dnb, const float* __restrict__ Wfe, const float* __restrict__ bfe,
    const float* __restrict__ We, const float* __restrict__ be, float* __restrict__ hE) {
  int e0 = blockIdx.x * EB_, t = threadIdx.x;
  __shared__ float feats[EB_ * 32];
  __shared__ __attribute__((aligned(16))) float buf[EB_ * H_];
  __shared__ float mstat[EB_], istat[EB_];
  #pragma unroll
  for (int p = 0; p < 4; p++) {
    int u = p * 4 + (t >> 5);
    int f = t & 31;
    int e = e0 + u;
    int n = (e / K_) % N_;
    float v;
    if (f < 16) {
      int jj = (f < 8) ? f : (f - 8);
      float freq = expf(-logf(10000.f) * (2.f * jj) / 16.f);
      float ang = (float)(E_idx[e] - n) * freq;
      v = (f < 8) ? cosf(ang) : sinf(ang);
    } else {
      int r = f - 16;
      float mu = 20.f * (float)r / 15.f;
      float z = (Dnb[e] - mu) * (1.f / 1.25f);
      v = expf(-z * z);
    }
    feats[u * 32 + f] = v;
  }
  __syncthreads();
  float acc[EB_];
  {
    float b0 = bfe[t];
    #pragma unroll
    for (int u = 0; u < EB_; u++) acc[u] = b0;
  }
  for (int f = 0; f < 32; f++) {
    float wv = Wfe[f * H_ + t];
    #pragma unroll
    for (int u = 0; u < EB_; u++) acc[u] = fmaf(feats[u * 32 + f], wv, acc[u]);
  }
  #pragma unroll
  for (int u = 0; u < EB_; u++) buf[u * H_ + t] = acc[u];
  __syncthreads();
  if (t < EB_) {
    float s = 0.f;
    for (int j0 = 0; j0 < H_; j0++) {
      int j = (j0 + t * 2) & (H_ - 1);
      s += buf[t * H_ + j];
    }
    float mean = s * (1.f / H_);
    float vs = 0.f;
    for (int j0 = 0; j0 < H_; j0++) {
      int j = (j0 + t * 2) & (H_ - 1);
      float d = buf[t * H_ + j] - mean;
      vs = fmaf(d, d, vs);
    }
    mstat[t] = mean;
    istat[t] = rsqrtf(vs * (1.f / H_) + 1e-6f);
  }
  __syncthreads();
  #pragma unroll
  for (int u = 0; u < EB_; u++) buf[u * H_ + t] = (acc[u] - mstat[u]) * istat[u];
  __syncthreads();
  float o[EB_];
  {
    float b0 = be[t];
    #pragma unroll
    for (int u = 0; u < EB_; u++) o[u] = b0;
  }
  for (int j4 = 0; j4 < H_ / 4; j4++) {
    int j = j4 * 4;
    float w0 = We[(j + 0) * H_ + t], w1 = We[(j + 1) * H_ + t];
    float w2 = We[(j + 2) * H_ + t], w3 = We[(j + 3) * H_ + t];
    #pragma unroll
    for (int u = 0; u < EB_; u++) {
      float4 xv = ((const float4*)(buf + u * H_))[j4];
      o[u] = fmaf(xv.x, w0, fmaf(xv.y, w1, fmaf(xv.z, w2, fmaf(xv.w, w3, o[u]))));
    }
  }
  #pragma unroll
  for (int u = 0; u < EB_; u++) hE[(size_t)(e0 + u) * H_ + t] = o[u];
}

// ---------------- per-node projection (encoder): oa/ob = x@Wa/Wb ----------------
__global__ __launch_bounds__(128) void node_proj_kernel(const float* __restrict__ x1,
    const float* __restrict__ Wa1, const float* __restrict__ Wb1,
    float* __restrict__ oa, float* __restrict__ ob) {
  constexpr int NT = 16;
  int n0 = blockIdx.x * NT, t = threadIdx.x;
  __shared__ __attribute__((aligned(16))) float xs1[NT * H_];
  #pragma unroll
  for (int u = 0; u < NT; u++) xs1[u * H_ + t] = x1[(size_t)(n0 + u) * H_ + t];
  __syncthreads();
  float aa[NT], ab[NT];
  #pragma unroll
  for (int u = 0; u < NT; u++) { aa[u] = 0.f; ab[u] = 0.f; }
  for (int j4 = 0; j4 < H_ / 4; j4++) {
    int j = j4 * 4;
    float wa0 = Wa1[(j + 0) * H_ + t], wa1 = Wa1[(j + 1) * H_ + t];
    float wa2 = Wa1[(j + 2) * H_ + t], wa3 = Wa1[(j + 3) * H_ + t];
    float wb0 = Wb1[(j + 0) * H_ + t], wb1 = Wb1[(j + 1) * H_ + t];
    float wb2 = Wb1[(j + 2) * H_ + t], wb3 = Wb1[(j + 3) * H_ + t];
    #pragma unroll
    for (int u = 0; u < NT; u++) {
      float4 xv = ((const float4*)(xs1 + u * H_))[j4];
      aa[u] = fmaf(xv.x, wa0, fmaf(xv.y, wa1, fmaf(xv.z, wa2, fmaf(xv.w, wa3, aa[u]))));
      ab[u] = fmaf(xv.x, wb0, fmaf(xv.y, wb1, fmaf(xv.z, wb2, fmaf(xv.w, wb3, ab[u]))));
    }
  }
  #pragma unroll
  for (int u = 0; u < NT; u++) {
    oa[(size_t)(n0 + u) * H_ + t] = aa[u];
    ob[(size_t)(n0 + u) * H_ + t] = ab[u];
  }
}

// ---------------- decoder fused projection: nKb/nVb = Ws[S]@WK2/WV2 + din@WK3/WV3 ;
//                  nKe/nVe = henc@WK3/WV3.  Ws gather inline; WK3/WV3 streamed once.
__global__ __launch_bounds__(128) void node_proj3_kernel(const int* __restrict__ S,
    const float* __restrict__ Ws, const float* __restrict__ din, const float* __restrict__ henc,
    const float* __restrict__ WK2, const float* __restrict__ WV2,
    const float* __restrict__ WK3, const float* __restrict__ WV3,
    float* __restrict__ nKb, float* __restrict__ nVb,
    float* __restrict__ nKe, float* __restrict__ nVe) {
  constexpr int NT = 8;
  int n0 = blockIdx.x * NT, t = threadIdx.x;
  __shared__ __attribute__((aligned(16))) float xs1[NT * H_];  // hS
  __shared__ __attribute__((aligned(16))) float xs2[NT * H_];  // din
  __shared__ __attribute__((aligned(16))) float xs3[NT * H_];  // henc
  #pragma unroll
  for (int u = 0; u < NT; u++) {
    int node = n0 + u;
    xs1[u * H_ + t] = Ws[(size_t)S[node] * H_ + t];
    xs2[u * H_ + t] = din[(size_t)node * H_ + t];
    xs3[u * H_ + t] = henc[(size_t)node * H_ + t];
  }
  __syncthreads();
  float aKb[NT], aVb[NT], aKe[NT], aVe[NT];
  #pragma unroll
  for (int u = 0; u < NT; u++) { aKb[u] = 0.f; aVb[u] = 0.f; aKe[u] = 0.f; aVe[u] = 0.f; }
  for (int j4 = 0; j4 < H_ / 4; j4++) {
    int j = j4 * 4;
    float k20 = WK2[(j + 0) * H_ + t], k21 = WK2[(j + 1) * H_ + t];
    float k22 = WK2[(j + 2) * H_ + t], k23 = WK2[(j + 3) * H_ + t];
    float v20 = WV2[(j + 0) * H_ + t], v21 = WV2[(j + 1) * H_ + t];
    float v22 = WV2[(j + 2) * H_ + t], v23 = WV2[(j + 3) * H_ + t];
    float k30 = WK3[(j + 0) * H_ + t], k31 = WK3[(j + 1) * H_ + t];
    float k32 = WK3[(j + 2) * H_ + t], k33 = WK3[(j + 3) * H_ + t];
    float v30 = WV3[(j + 0) * H_ + t], v31 = WV3[(j + 1) * H_ + t];
    float v32 = WV3[(j + 2) * H_ + t], v33 = WV3[(j + 3) * H_ + t];
    #pragma unroll
    for (int u = 0; u < NT; u++) {
      float4 a = ((const float4*)(xs1 + u * H_))[j4];
      float4 b = ((const float4*)(xs2 + u * H_))[j4];
      float4 c = ((const float4*)(xs3 + u * H_))[j4];
      aKb[u] = fmaf(a.x, k20, fmaf(a.y, k21, fmaf(a.z, k22, fmaf(a.w, k23, aKb[u]))));
      aKb[u] = fmaf(b.x, k30, fmaf(b.y, k31, fmaf(b.z, k32, fmaf(b.w, k33, aKb[u]))));
      aVb[u] = fmaf(a.x, v20, fmaf(a.y, v21, fmaf(a.z, v22, fmaf(a.w, v23, aVb[u]))));
      aVb[u] = fmaf(b.x, v30, fmaf(b.y, v31, fmaf(b.z, v32, fmaf(b.w, v33, aVb[u]))));
      aKe[u] = fmaf(c.x, k30, fmaf(c.y, k31, fmaf(c.z, k32, fmaf(c.w, k33, aKe[u]))));
      aVe[u] = fmaf(c.x, v30, fmaf(c.y, v31, fmaf(c.z, v32, fmaf(c.w, v33, aVe[u]))));
    }
  }
  #pragma unroll
  for (int u = 0; u < NT; u++) {
    size_t g = (size_t)(n0 + u) * H_ + t;
    nKb[g] = aKb[u]; nVb[g] = aVb[u]; nKe[g] = aKe[u]; nVe[g] = aVe[u];
  }
}

// ---------------- fused graph attention + residual LN ----------------
// Low-LDS version: hE staged chunk-by-chunk (KT=10, 5 KB), combined V kept in 30
// per-thread registers (R10 precedent: 64 VGPRs) -> ~7.7 KB LDS, occupancy ~2x.
template<bool ENC>
__global__ __launch_bounds__(H_) void attn_kernel(const float* __restrict__ hV_in,
    const float* __restrict__ hE, const int* __restrict__ E_idx, const float* __restrict__ mask,
    const float* __restrict__ WQ, const float* __restrict__ WK1,
    const float* __restrict__ WV1, const float* __restrict__ WO,
    const float* __restrict__ nKb, const float* __restrict__ nVb,
    const float* __restrict__ nKe, const float* __restrict__ nVe,
    float* __restrict__ hV_out) {
  constexpr int KT = 10;
  const int node = blockIdx.x;
  const int b = node / N_, n = node % N_;
  const int t = threadIdx.x;
  const int head = t >> 5, lane32 = t & 31;
  __shared__ __attribute__((aligned(16))) float x0[H_];
  __shared__ __attribute__((aligned(16))) float xs[KT * H_];
  __shared__ __attribute__((aligned(16))) float ob[H_];
  __shared__ float sc[NH_ * K_];
  __shared__ float att[NH_ * K_];
  __shared__ float red[H_];
  __shared__ int nbs[K_];

  x0[t] = hV_in[(size_t)node * H_ + t];
  if (t < K_) nbs[t] = E_idx[node * K_ + t];
  __syncthreads();

  float qreg = 0.f;
  for (int j4 = 0; j4 < H_ / 4; j4++) {
    float4 xv = ((const float4*)x0)[j4];
    int j = j4 * 4;
    qreg = fmaf(xv.x, WQ[(j + 0) * H_ + t],
           fmaf(xv.y, WQ[(j + 1) * H_ + t],
           fmaf(xv.z, WQ[(j + 2) * H_ + t],
           fmaf(xv.w, WQ[(j + 3) * H_ + t], qreg))));
  }
  float mi = mask[b * N_ + n];

  float vvAll[K_];  // combined V rows for this thread's column
  for (int kt = 0; kt < K_; kt += KT) {
    // stage this chunk's hE rows (contiguous, coalesced)
    {
      const float* src = hE + ((size_t)node * K_ + kt) * H_;
      for (int i = t; i < KT * H_; i += H_) xs[i] = src[i];
    }
    __syncthreads();
    float kv[KT], vv[KT];
    #pragma unroll
    for (int u = 0; u < KT; u++) { kv[u] = 0.f; vv[u] = 0.f; }
    for (int j4 = 0; j4 < H_ / 4; j4++) {
      int j = j4 * 4;
      float wk0 = WK1[(j + 0) * H_ + t], wk1 = WK1[(j + 1) * H_ + t];
      float wk2 = WK1[(j + 2) * H_ + t], wk3 = WK1[(j + 3) * H_ + t];
      float wv0 = WV1[(j + 0) * H_ + t], wv1 = WV1[(j + 1) * H_ + t];
      float wv2 = WV1[(j + 2) * H_ + t], wv3 = WV1[(j + 3) * H_ + t];
      #pragma unroll
      for (int u = 0; u < KT; u++) {
        float4 xv = *((const float4*)(xs + u * H_ + j));
        kv[u] = fmaf(xv.x, wk0, fmaf(xv.y, wk1, fmaf(xv.z, wk2, fmaf(xv.w, wk3, kv[u]))));
        vv[u] = fmaf(xv.x, wv0, fmaf(xv.y, wv1, fmaf(xv.z, wv2, fmaf(xv.w, wv3, vv[u]))));
      }
    }
    __syncthreads();  // chunk reads complete before next staging overwrites xs
    #pragma unroll
    for (int u = 0; u < KT; u++) {
      int k = kt + u;
      int nb = nbs[k];
      size_t nbg = (size_t)(b * N_ + nb) * H_ + t;
      float kvt, vvt;
      if (ENC) {
        kvt = kv[u] + nKb[nbg];
        vvt = vv[u] + nVb[nbg];
      } else {
        float ar = (nb < n) ? 1.f : 0.f;
        float bw = mi * ar, fw = mi * (1.f - ar);
        kvt = fmaf(mi, kv[u], fmaf(bw, nKb[nbg], fw * nKe[nbg]));
        vvt = fmaf(mi, vv[u], fmaf(bw, nVb[nbg], fw * nVe[nbg]));
      }
      vvAll[k] = vvt;
      float prod = qreg * kvt;
      #pragma unroll
      for (int off = 16; off > 0; off >>= 1) prod += __shfl_xor(prod, off, 32);
      if (lane32 == 0) {
        float lg = prod * 0.17677669529663687f;  // 1/sqrt(32)
        if (ENC) {
          float m2 = mi * mask[b * N_ + nb];
          sc[head * K_ + k] = (m2 > 0.f) ? lg : NEG_INF_;
        } else {
          sc[head * K_ + k] = lg;
        }
      }
    }
  }
  __syncthreads();

  if (t < NH_) {
    float mx = -3.4e38f;
    for (int k = 0; k < K_; k++) mx = fmaxf(mx, sc[t * K_ + k]);
    float s = 0.f;
    for (int k = 0; k < K_; k++) { float ev = expf(sc[t * K_ + k] - mx); att[t * K_ + k] = ev; s += ev; }
    float inv = 1.f / s;
    for (int k = 0; k < K_; k++) att[t * K_ + k] *= inv;
  }
  __syncthreads();
  if (ENC && t < K_) {
    float m2 = mi * mask[b * N_ + nbs[t]];
    for (int hh = 0; hh < NH_; hh++) att[hh * K_ + t] *= m2;
  }
  __syncthreads();
  float o = 0.f;
  #pragma unroll
  for (int k = 0; k < K_; k++) o = fmaf(att[head * K_ + k], vvAll[k], o);
  ob[t] = o; __syncthreads();
  float dh = 0.f;
  for (int j4 = 0; j4 < H_ / 4; j4++) {
    float4 ov = ((const float4*)ob)[j4];
    int j = j4 * 4;
    dh = fmaf(ov.x, WO[(j + 0) * H_ + t],
         fmaf(ov.y, WO[(j + 1) * H_ + t],
         fmaf(ov.z, WO[(j + 2) * H_ + t],
         fmaf(ov.w, WO[(j + 3) * H_ + t], dh))));
  }
  float r = x0[t] + dh;
  float mean = block_sum128f(r, red) * (1.f / H_);
  float d0 = r - mean;
  float var = block_sum128f(d0 * d0, red) * (1.f / H_);
  hV_out[(size_t)node * H_ + t] = d0 * rsqrtf(var + 1e-6f);
}

// ---------------- FFN, FB=8 nodes/block: LN(x + relu(x@W1+b1)@W2+b2) * mask ----------------
constexpr int FB_ = 8;
__global__ __launch_bounds__(H_) void ffn_kernel(float* __restrict__ hV, const float* __restrict__ mask,
    const float* __restrict__ W1, const float* __restrict__ b1,
    const float* __restrict__ W2, const float* __restrict__ b2) {
  int n0 = blockIdx.x * FB_, t = threadIdx.x;
  __shared__ __attribute__((aligned(16))) float x[FB_ * H_];
  __shared__ __attribute__((aligned(16))) float hid[FB_ * 4 * H_];
  __shared__ float mstat[FB_], istat[FB_];
  #pragma unroll
  for (int u = 0; u < FB_; u++) x[u * H_ + t] = hV[(size_t)(n0 + u) * H_ + t];
  __syncthreads();
  for (int c = 0; c < 4; c++) {
    float acc[FB_];
    float b0 = b1[c * H_ + t];
    #pragma unroll
    for (int u = 0; u < FB_; u++) acc[u] = b0;
    for (int h4 = 0; h4 < H_ / 4; h4++) {
      int h = h4 * 4;
      float w0 = W1[(h + 0) * 4 * H_ + c * H_ + t];
      float w1 = W1[(h + 1) * 4 * H_ + c * H_ + t];
      float w2 = W1[(h + 2) * 4 * H_ + c * H_ + t];
      float w3 = W1[(h + 3) * 4 * H_ + c * H_ + t];
      #pragma unroll
      for (int u = 0; u < FB_; u++) {
        float4 xv = ((const float4*)(x + u * H_))[h4];
        acc[u] = fmaf(xv.x, w0, fmaf(xv.y, w1, fmaf(xv.z, w2, fmaf(xv.w, w3, acc[u]))));
      }
    }
    #pragma unroll
    for (int u = 0; u < FB_; u++) hid[u * 4 * H_ + c * H_ + t] = fmaxf(acc[u], 0.f);
  }
  __syncthreads();
  float o[FB_];
  {
    float b0 = b2[t];
    #pragma unroll
    for (int u = 0; u < FB_; u++) o[u] = b0;
  }
  for (int j4 = 0; j4 < (4 * H_) / 4; j4++) {
    int j = j4 * 4;
    float w0 = W2[(j + 0) * H_ + t], w1 = W2[(j + 1) * H_ + t];
    float w2 = W2[(j + 2) * H_ + t], w3 = W2[(j + 3) * H_ + t];
    #pragma unroll
    for (int u = 0; u < FB_; u++) {
      float4 hv = ((const float4*)(hid + u * 4 * H_))[j4];
      o[u] = fmaf(hv.x, w0, fmaf(hv.y, w1, fmaf(hv.z, w2, fmaf(hv.w, w3, o[u]))));
    }
  }
  float r[FB_];
  #pragma unroll
  for (int u = 0; u < FB_; u++) r[u] = x[u * H_ + t] + o[u];
  __syncthreads();
  #pragma unroll
  for (int u = 0; u < FB_; u++) x[u * H_ + t] = r[u];
  __syncthreads();
  if (t < FB_) {
    float s = 0.f;
    for (int j0 = 0; j0 < H_; j0++) {
      int j = (j0 + t * 2) & (H_ - 1);
      s += x[t * H_ + j];
    }
    float mean = s * (1.f / H_);
    float vs = 0.f;
    for (int j0 = 0; j0 < H_; j0++) {
      int j = (j0 + t * 2) & (H_ - 1);
      float d = x[t * H_ + j] - mean;
      vs = fmaf(d, d, vs);
    }
    mstat[t] = mean;
    istat[t] = rsqrtf(vs * (1.f / H_) + 1e-6f);
  }
  __syncthreads();
  #pragma unroll
  for (int u = 0; u < FB_; u++) {
    float y = (r[u] - mstat[u]) * istat[u];
    y *= mask[n0 + u];
    hV[(size_t)(n0 + u) * H_ + t] = y;
  }
}

// ---------------- output: log_softmax(hV @ W_out + b_out), fp32, 2 nodes/block ----------------
__global__ __launch_bounds__(128) void out_kernel(const float* __restrict__ hV,
    const float* __restrict__ Wout, const float* __restrict__ bout, float* __restrict__ out) {
  int g = threadIdx.x >> 6, t = threadIdx.x & 63;
  int node = blockIdx.x * 2 + g;
  __shared__ float x[2][H_];
  __shared__ float lg[2][V_];
  __shared__ float lse[2];
  x[g][t] = hV[(size_t)node * H_ + t];
  x[g][t + 64] = hV[(size_t)node * H_ + t + 64];
  __syncthreads();
  if (t < V_) {
    float a = bout[t];
    for (int h = 0; h < H_; h++) a = fmaf(x[g][h], Wout[h * V_ + t], a);
    lg[g][t] = a;
  }
  __syncthreads();
  if (t == 0) {
    float mx = -3.4e38f;
    for (int v = 0; v < V_; v++) mx = fmaxf(mx, lg[g][v]);
    float s = 0.f;
    for (int v = 0; v < V_; v++) s += expf(lg[g][v] - mx);
    lse[g] = mx + logf(s);
  }
  __syncthreads();
  if (t < V_) out[(size_t)node * V_ + t] = lg[g][t] - lse[g];
}

// ---------------- host ----------------
extern "C" void kernel_launch(void* const* d_in, const int* in_sizes, int n_in,
                              void* d_out, int out_size, void* d_ws, size_t ws_size,
                              hipStream_t stream) {
  const float* X    = (const float*)d_in[0];
  const float* mask = (const float*)d_in[1];
  const int*   S    = (const int*)d_in[2];
  const float* Wfn  = (const float*)d_in[3];
  const float* bfn  = (const float*)d_in[4];
  const float* Wfe  = (const float*)d_in[5];
  const float* bfe  = (const float*)d_in[6];
  const float* Wv   = (const float*)d_in[7];
  const float* bv   = (const float*)d_in[8];
  const float* We   = (const float*)d_in[9];
  const float* be   = (const float*)d_in[10];
  const float* Ws   = (const float*)d_in[11];
  const float* eWQ  = (const float*)d_in[12];
  const float* eWK  = (const float*)d_in[13];
  const float* eWV  = (const float*)d_in[14];
  const float* eWO  = (const float*)d_in[15];
  const float* eW1  = (const float*)d_in[16];
  const float* eb1  = (const float*)d_in[17];
  const float* eW2  = (const float*)d_in[18];
  const float* eb2  = (const float*)d_in[19];
  const float* dWQ  = (const float*)d_in[20];
  const float* dWK  = (const float*)d_in[21];
  const float* dWV  = (const float*)d_in[22];
  const float* dWO  = (const float*)d_in[23];
  const float* dW1  = (const float*)d_in[24];
  const float* db1  = (const float*)d_in[25];
  const float* dW2  = (const float*)d_in[26];
  const float* db2  = (const float*)d_in[27];
  const float* Wout = (const float*)d_in[28];
  const float* bout = (const float*)d_in[29];
  float* out = (float*)d_out;

  char* w = (char*)d_ws;
  int*    eidx = (int*)w;     w += (size_t)BN_ * K_ * 4;
  float*  dnb  = (float*)w;   w += (size_t)BN_ * K_ * 4;
  float*  vf   = (float*)w;   w += (size_t)BN_ * 6 * 4;
  float*  hVa  = (float*)w;   w += (size_t)BN_ * H_ * 4;
  float*  hVb  = (float*)w;   w += (size_t)BN_ * H_ * 4;
  float*  hVc  = (float*)w;   w += (size_t)BN_ * H_ * 4;
  float*  nKb  = (float*)w;   w += (size_t)BN_ * H_ * 4;
  float*  nVb  = (float*)w;   w += (size_t)BN_ * H_ * 4;
  float*  nKe  = (float*)w;   w += (size_t)BN_ * H_ * 4;
  float*  nVe  = (float*)w;   w += (size_t)BN_ * H_ * 4;
  float*  hE   = (float*)w;   w += (size_t)BN_ * K_ * H_ * 4;

  topk_kernel<<<BN_, 256, 0, stream>>>(X, mask, eidx, dnb);
  dihedral_kernel<<<(BN_ + 255) / 256, 256, 0, stream>>>(X, vf);
  node_embed_kernel<<<BN_, H_, 0, stream>>>(vf, Wfn, bfn, Wv, bv, hVa);
  edge_embed_kernel<<<BN_ * K_ / EB_, H_, 0, stream>>>(eidx, dnb, Wfe, bfe, We, be, hE);

  // encoder: a->b, b->a, a->b
  float* cur = hVa; float* nxt = hVb;
  for (int l = 0; l < 3; l++) {
    const float* WK = eWK + (size_t)l * 2 * H_ * H_;
    const float* WV = eWV + (size_t)l * 2 * H_ * H_;
    node_proj_kernel<<<BN_ / 16, H_, 0, stream>>>(cur,
        WK + (size_t)H_ * H_, WV + (size_t)H_ * H_, nKb, nVb);
    attn_kernel<true><<<BN_, H_, 0, stream>>>(cur, hE, eidx, mask,
        eWQ + (size_t)l * H_ * H_, WK, WV, eWO + (size_t)l * H_ * H_,
        nKb, nVb, nullptr, nullptr, nxt);
    ffn_kernel<<<BN_ / FB_, H_, 0, stream>>>(nxt, mask,
        eW1 + (size_t)l * H_ * 4 * H_, eb1 + (size_t)l * 4 * H_,
        eW2 + (size_t)l * 4 * H_ * H_, eb2 + (size_t)l * H_);
    float* tmp = cur; cur = nxt; nxt = tmp;
  }
  float* henc = cur;  // = hVb
  // decoder: henc->a, a->c, c->a (henc preserved)
  float* din = henc;
  float* douts[3] = { hVa, hVc, hVa };
  for (int l = 0; l < 3; l++) {
    const float* WK = dWK + (size_t)l * 3 * H_ * H_;
    const float* WV = dWV + (size_t)l * 3 * H_ * H_;
    node_proj3_kernel<<<BN_ / 8, H_, 0, stream>>>(S, Ws, din, henc,
        WK + (size_t)H_ * H_, WV + (size_t)H_ * H_,
        WK + (size_t)2 * H_ * H_, WV + (size_t)2 * H_ * H_,
        nKb, nVb, nKe, nVe);
    attn_kernel<false><<<BN_, H_, 0, stream>>>(din, hE, eidx, mask,
        dWQ + (size_t)l * H_ * H_, WK, WV, dWO + (size_t)l * H_ * H_,
        nKb, nVb, nKe, nVe, douts[l]);
    ffn_kernel<<<BN_ / FB_, H_, 0, stream>>>(douts[l], mask,
        dW1 + (size_t)l * H_ * 4 * H_, db1 + (size_t)l * 4 * H_,
        dW2 + (size_t)l * 4 * H_ * H_, db2 + (size_t)l * H_);
    din = douts[l];
  }
  out_kernel<<<BN_ / 2, 128, 0, stream>>>(din, Wout, bout, out);
}

// Round 18
// 3459.411 us; speedup vs baseline: 1.0378x; 1.0378x over previous
//
#include <hip/hip_runtime.h>
#include <hip/hip_bf16.h>
#include <math.h>

#define DEVFN __device__ __forceinline__

constexpr int B_ = 16, N_ = 512, K_ = 30, H_ = 128;
constexpr int NH_ = 4, V_ = 20;
constexpr int BN_ = B_ * N_;
constexpr float NEG_INF_ = -3.4028235e38f;

DEVFN float block_sum128f(float v, float* sbuf) {
  int t = threadIdx.x;
  sbuf[t] = v; __syncthreads();
  #pragma unroll
  for (int s = 64; s > 0; s >>= 1) {
    if (t < s) sbuf[t] += sbuf[t + s];
    __syncthreads();
  }
  float r = sbuf[0];
  __syncthreads();
  return r;
}

// ---------------- top-K neighbors: distances BIT-EXACT to plain numpy float32 ----------------
// DO NOT TOUCH the distance math / tie-break: bit-exact __f*_rn distance + higher-index
// tie-break matches the np reference at exact ties (bf16-valued coords) — R8 fix.
__global__ __launch_bounds__(256) void topk_kernel(const float* __restrict__ X,
    const float* __restrict__ mask, int* __restrict__ E_idx, float* __restrict__ Dnb) {
  __shared__ float xs[N_ * 3];
  __shared__ float ds[N_];
  __shared__ float fred[256];
  __shared__ unsigned long long kred[4];
  int b = blockIdx.x / N_, i = blockIdx.x % N_;
  int t = threadIdx.x;
  for (int j = t; j < N_; j += 256) {
    const float* p = X + ((size_t)(b * N_ + j) * 4 + 1) * 3;  // CA atom
    xs[j * 3 + 0] = p[0]; xs[j * 3 + 1] = p[1]; xs[j * 3 + 2] = p[2];
  }
  __syncthreads();
  float xi0 = xs[i * 3], xi1 = xs[i * 3 + 1], xi2 = xs[i * 3 + 2];
  float mi = mask[b * N_ + i];
  float lmax = -3.4e38f;
  for (int j = t; j < N_; j += 256) {
    float dx = __fsub_rn(xi0, xs[j * 3]);
    float dy = __fsub_rn(xi1, xs[j * 3 + 1]);
    float dz = __fsub_rn(xi2, xs[j * 3 + 2]);
    float m2 = __fmul_rn(mi, mask[b * N_ + j]);
    float s = __fadd_rn(__fadd_rn(__fadd_rn(__fmul_rn(dx, dx), __fmul_rn(dy, dy)),
                                  __fmul_rn(dz, dz)), 1e-6f);
    float D = __fmul_rn(m2, __fsqrt_rn(s));
    ds[j] = D;
    lmax = fmaxf(lmax, D);
  }
  fred[t] = lmax; __syncthreads();
  for (int s = 128; s > 0; s >>= 1) { if (t < s) fred[t] = fmaxf(fred[t], fred[t + s]); __syncthreads(); }
  float Dmax = fred[0]; __syncthreads();
  for (int j = t; j < N_; j += 256) {
    float m2 = __fmul_rn(mi, mask[b * N_ + j]);
    ds[j] = __fadd_rn(ds[j], __fmul_rn(__fsub_rn(1.f, m2), Dmax));
  }
  __syncthreads();
  // extract K smallest; equal distances -> HIGHER index first (key = dist || N-1-j)
  int lane = t & 63, wv = t >> 6;
  for (int kk = 0; kk < K_; kk++) {
    unsigned long long best = ~0ull;
    for (int j = t; j < N_; j += 256) {
      unsigned long long key = (((unsigned long long)__float_as_uint(ds[j])) << 32)
                             | (unsigned)(N_ - 1 - j);
      if (key < best) best = key;
    }
    #pragma unroll
    for (int off = 32; off > 0; off >>= 1) {
      unsigned long long o = __shfl_xor(best, off, 64);
      if (o < best) best = o;
    }
    if (lane == 0) kred[wv] = best;
    __syncthreads();
    if (t == 0) {
      unsigned long long k0 = kred[0];
      if (kred[1] < k0) k0 = kred[1];
      if (kred[2] < k0) k0 = kred[2];
      if (kred[3] < k0) k0 = kred[3];
      int j = N_ - 1 - (int)(k0 & 0xffffffffull);
      E_idx[blockIdx.x * K_ + kk] = j;
      Dnb[blockIdx.x * K_ + kk] = __uint_as_float((unsigned)(k0 >> 32));
      ds[j] = 3.4028235e38f;
    }
    __syncthreads();
  }
}

// ---------------- dihedral features (1 thread / node), fp32 ----------------
DEVFN void load_atom(const float* X, int b, int m, float* p) {
  const float* q = X + ((size_t)(b * N_ + m / 3) * 4 + (m % 3)) * 3;
  p[0] = q[0]; p[1] = q[1]; p[2] = q[2];
}
DEVFN void cross3(const float* a, const float* b, float* c) {
  c[0] = a[1] * b[2] - a[2] * b[1];
  c[1] = a[2] * b[0] - a[0] * b[2];
  c[2] = a[0] * b[1] - a[1] * b[0];
}
DEVFN void norm3(float* v) {
  float n = sqrtf(v[0] * v[0] + v[1] * v[1] + v[2] * v[2]) + 1e-7f;
  v[0] /= n; v[1] /= n; v[2] /= n;
}
__global__ __launch_bounds__(256) void dihedral_kernel(const float* __restrict__ X, float* __restrict__ Vf) {
  int idx = blockIdx.x * blockDim.x + threadIdx.x;
  if (idx >= BN_) return;
  int b = idx / N_, n = idx % N_;
  float cs[3], sn[3];
  for (int s = 0; s < 3; s++) {
    int p = 3 * n + s;
    float a = 0.f;
    if (p >= 1 && p <= 3 * N_ - 3) {
      int tt = p - 1;
      float u[3][3], prev[3], cur[3];
      load_atom(X, b, tt, prev);
      for (int q = 0; q < 3; q++) {
        load_atom(X, b, tt + q + 1, cur);
        float d0 = cur[0] - prev[0], d1 = cur[1] - prev[1], d2 = cur[2] - prev[2];
        float nr = sqrtf(d0 * d0 + d1 * d1 + d2 * d2) + 1e-7f;
        u[q][0] = d0 / nr; u[q][1] = d1 / nr; u[q][2] = d2 / nr;
        prev[0] = cur[0]; prev[1] = cur[1]; prev[2] = cur[2];
      }
      float n2v[3], n1v[3];
      cross3(u[0], u[1], n2v); norm3(n2v);
      cross3(u[1], u[2], n1v); norm3(n1v);
      float cd = n2v[0] * n1v[0] + n2v[1] * n1v[1] + n2v[2] * n1v[2];
      cd = fminf(fmaxf(cd, -1.f + 1e-7f), 1.f - 1e-7f);
      float dt = u[0][0] * n1v[0] + u[0][1] * n1v[1] + u[0][2] * n1v[2];
      float sg = (dt > 0.f) ? 1.f : ((dt < 0.f) ? -1.f : 0.f);
      a = sg * acosf(cd);
    }
    cs[s] = cosf(a); sn[s] = sinf(a);
  }
  float* o = Vf + (size_t)idx * 6;
  o[0] = cs[0]; o[1] = cs[1]; o[2] = cs[2]; o[3] = sn[0]; o[4] = sn[1]; o[5] = sn[2];
}

// ---------------- node embed: hV = LN(V@Wfn+bfn) @ Wv + bv (fp32) ----------------
__global__ __launch_bounds__(H_) void node_embed_kernel(const float* __restrict__ Vf,
    const float* __restrict__ Wfn, const float* __restrict__ bfn,
    const float* __restrict__ Wv, const float* __restrict__ bv, float* __restrict__ hV) {
  int node = blockIdx.x, t = threadIdx.x;
  __shared__ float v6[6];
  __shared__ float t1[H_];
  __shared__ float red[H_];
  if (t < 6) v6[t] = Vf[(size_t)node * 6 + t];
  __syncthreads();
  float acc = bfn[t];
  for (int f = 0; f < 6; f++) acc = fmaf(v6[f], Wfn[f * H_ + t], acc);
  float mean = block_sum128f(acc, red) * (1.f / H_);
  float d0 = acc - mean;
  float var = block_sum128f(d0 * d0, red) * (1.f / H_);
  t1[t] = d0 * rsqrtf(var + 1e-6f);
  __syncthreads();
  float o = bv[t];
  for (int j = 0; j < H_; j++) o = fmaf(t1[j], Wv[j * H_ + t], o);
  hV[(size_t)node * H_ + t] = o;
}

// ---------------- edge embed, EB=16 edges/block: hE = LN(E@Wfe+bfe) @ We + be ----------------
constexpr int EB_ = 16;
__global__ __launch_bounds__(H_) void edge_embed_kernel(const int* __restrict__ E_idx,
    const float* __restrict__ Dnb, const float* __restrict__ Wfe, const float* __restrict__ bfe,
    const float* __restrict__ We, const float* __restrict__ be, float* __restrict__ hE) {
  int e0 = blockIdx.x * EB_, t = threadIdx.x;
  __shared__ float feats[EB_ * 32];
  __shared__ __attribute__((aligned(16))) float buf[EB_ * H_];
  __shared__ float mstat[EB_], istat[EB_];
  #pragma unroll
  for (int p = 0; p < 4; p++) {
    int u = p * 4 + (t >> 5);
    int f = t & 31;
    int e = e0 + u;
    int n = (e / K_) % N_;
    float v;
    if (f < 16) {
      int jj = (f < 8) ? f : (f - 8);
      float freq = expf(-logf(10000.f) * (2.f * jj) / 16.f);
      float ang = (float)(E_idx[e] - n) * freq;
      v = (f < 8) ? cosf(ang) : sinf(ang);
    } else {
      int r = f - 16;
      float mu = 20.f * (float)r / 15.f;
      float z = (Dnb[e] - mu) * (1.f / 1.25f);
      v = expf(-z * z);
    }
    feats[u * 32 + f] = v;
  }
  __syncthreads();
  float acc[EB_];
  {
    float b0 = bfe[t];
    #pragma unroll
    for (int u = 0; u < EB_; u++) acc[u] = b0;
  }
  for (int f = 0; f < 32; f++) {
    float wv = Wfe[f * H_ + t];
    #pragma unroll
    for (int u = 0; u < EB_; u++) acc[u] = fmaf(feats[u * 32 + f], wv, acc[u]);
  }
  #pragma unroll
  for (int u = 0; u < EB_; u++) buf[u * H_ + t] = acc[u];
  __syncthreads();
  if (t < EB_) {
    float s = 0.f;
    for (int j0 = 0; j0 < H_; j0++) {
      int j = (j0 + t * 2) & (H_ - 1);
      s += buf[t * H_ + j];
    }
    float mean = s * (1.f / H_);
    float vs = 0.f;
    for (int j0 = 0; j0 < H_; j0++) {
      int j = (j0 + t * 2) & (H_ - 1);
      float d = buf[t * H_ + j] - mean;
      vs = fmaf(d, d, vs);
    }
    mstat[t] = mean;
    istat[t] = rsqrtf(vs * (1.f / H_) + 1e-6f);
  }
  __syncthreads();
  #pragma unroll
  for (int u = 0; u < EB_; u++) buf[u * H_ + t] = (acc[u] - mstat[u]) * istat[u];
  __syncthreads();
  float o[EB_];
  {
    float b0 = be[t];
    #pragma unroll
    for (int u = 0; u < EB_; u++) o[u] = b0;
  }
  for (int j4 = 0; j4 < H_ / 4; j4++) {
    int j = j4 * 4;
    float w0 = We[(j + 0) * H_ + t], w1 = We[(j + 1) * H_ + t];
    float w2 = We[(j + 2) * H_ + t], w3 = We[(j + 3) * H_ + t];
    #pragma unroll
    for (int u = 0; u < EB_; u++) {
      float4 xv = ((const float4*)(buf + u * H_))[j4];
      o[u] = fmaf(xv.x, w0, fmaf(xv.y, w1, fmaf(xv.z, w2, fmaf(xv.w, w3, o[u]))));
    }
  }
  #pragma unroll
  for (int u = 0; u < EB_; u++) hE[(size_t)(e0 + u) * H_ + t] = o[u];
}

// ---------------- per-node projection (encoder): oa/ob = x@Wa/Wb ----------------
__global__ __launch_bounds__(128) void node_proj_kernel(const float* __restrict__ x1,
    const float* __restrict__ Wa1, const float* __restrict__ Wb1,
    float* __restrict__ oa, float* __restrict__ ob) {
  constexpr int NT = 16;
  int n0 = blockIdx.x * NT, t = threadIdx.x;
  __shared__ __attribute__((aligned(16))) float xs1[NT * H_];
  #pragma unroll
  for (int u = 0; u < NT; u++) xs1[u * H_ + t] = x1[(size_t)(n0 + u) * H_ + t];
  __syncthreads();
  float aa[NT], ab[NT];
  #pragma unroll
  for (int u = 0; u < NT; u++) { aa[u] = 0.f; ab[u] = 0.f; }
  for (int j4 = 0; j4 < H_ / 4; j4++) {
    int j = j4 * 4;
    float wa0 = Wa1[(j + 0) * H_ + t], wa1 = Wa1[(j + 1) * H_ + t];
    float wa2 = Wa1[(j + 2) * H_ + t], wa3 = Wa1[(j + 3) * H_ + t];
    float wb0 = Wb1[(j + 0) * H_ + t], wb1 = Wb1[(j + 1) * H_ + t];
    float wb2 = Wb1[(j + 2) * H_ + t], wb3 = Wb1[(j + 3) * H_ + t];
    #pragma unroll
    for (int u = 0; u < NT; u++) {
      float4 xv = ((const float4*)(xs1 + u * H_))[j4];
      aa[u] = fmaf(xv.x, wa0, fmaf(xv.y, wa1, fmaf(xv.z, wa2, fmaf(xv.w, wa3, aa[u]))));
      ab[u] = fmaf(xv.x, wb0, fmaf(xv.y, wb1, fmaf(xv.z, wb2, fmaf(xv.w, wb3, ab[u]))));
    }
  }
  #pragma unroll
  for (int u = 0; u < NT; u++) {
    oa[(size_t)(n0 + u) * H_ + t] = aa[u];
    ob[(size_t)(n0 + u) * H_ + t] = ab[u];
  }
}

// ---------------- decoder fused projection: nKb/nVb = Ws[S]@WK2/WV2 + din@WK3/WV3 ;
//                  nKe/nVe = henc@WK3/WV3.  Ws gather inline; WK3/WV3 streamed once.
__global__ __launch_bounds__(128) void node_proj3_kernel(const int* __restrict__ S,
    const float* __restrict__ Ws, const float* __restrict__ din, const float* __restrict__ henc,
    const float* __restrict__ WK2, const float* __restrict__ WV2,
    const float* __restrict__ WK3, const float* __restrict__ WV3,
    float* __restrict__ nKb, float* __restrict__ nVb,
    float* __restrict__ nKe, float* __restrict__ nVe) {
  constexpr int NT = 8;
  int n0 = blockIdx.x * NT, t = threadIdx.x;
  __shared__ __attribute__((aligned(16))) float xs1[NT * H_];  // hS
  __shared__ __attribute__((aligned(16))) float xs2[NT * H_];  // din
  __shared__ __attribute__((aligned(16))) float xs3[NT * H_];  // henc
  #pragma unroll
  for (int u = 0; u < NT; u++) {
    int node = n0 + u;
    xs1[u * H_ + t] = Ws[(size_t)S[node] * H_ + t];
    xs2[u * H_ + t] = din[(size_t)node * H_ + t];
    xs3[u * H_ + t] = henc[(size_t)node * H_ + t];
  }
  __syncthreads();
  float aKb[NT], aVb[NT], aKe[NT], aVe[NT];
  #pragma unroll
  for (int u = 0; u < NT; u++) { aKb[u] = 0.f; aVb[u] = 0.f; aKe[u] = 0.f; aVe[u] = 0.f; }
  for (int j4 = 0; j4 < H_ / 4; j4++) {
    int j = j4 * 4;
    float k20 = WK2[(j + 0) * H_ + t], k21 = WK2[(j + 1) * H_ + t];
    float k22 = WK2[(j + 2) * H_ + t], k23 = WK2[(j + 3) * H_ + t];
    float v20 = WV2[(j + 0) * H_ + t], v21 = WV2[(j + 1) * H_ + t];
    float v22 = WV2[(j + 2) * H_ + t], v23 = WV2[(j + 3) * H_ + t];
    float k30 = WK3[(j + 0) * H_ + t], k31 = WK3[(j + 1) * H_ + t];
    float k32 = WK3[(j + 2) * H_ + t], k33 = WK3[(j + 3) * H_ + t];
    float v30 = WV3[(j + 0) * H_ + t], v31 = WV3[(j + 1) * H_ + t];
    float v32 = WV3[(j + 2) * H_ + t], v33 = WV3[(j + 3) * H_ + t];
    #pragma unroll
    for (int u = 0; u < NT; u++) {
      float4 a = ((const float4*)(xs1 + u * H_))[j4];
      float4 b = ((const float4*)(xs2 + u * H_))[j4];
      float4 c = ((const float4*)(xs3 + u * H_))[j4];
      aKb[u] = fmaf(a.x, k20, fmaf(a.y, k21, fmaf(a.z, k22, fmaf(a.w, k23, aKb[u]))));
      aKb[u] = fmaf(b.x, k30, fmaf(b.y, k31, fmaf(b.z, k32, fmaf(b.w, k33, aKb[u]))));
      aVb[u] = fmaf(a.x, v20, fmaf(a.y, v21, fmaf(a.z, v22, fmaf(a.w, v23, aVb[u]))));
      aVb[u] = fmaf(b.x, v30, fmaf(b.y, v31, fmaf(b.z, v32, fmaf(b.w, v33, aVb[u]))));
      aKe[u] = fmaf(c.x, k30, fmaf(c.y, k31, fmaf(c.z, k32, fmaf(c.w, k33, aKe[u]))));
      aVe[u] = fmaf(c.x, v30, fmaf(c.y, v31, fmaf(c.z, v32, fmaf(c.w, v33, aVe[u]))));
    }
  }
  #pragma unroll
  for (int u = 0; u < NT; u++) {
    size_t g = (size_t)(n0 + u) * H_ + t;
    nKb[g] = aKb[u]; nVb[g] = aVb[u]; nKe[g] = aKe[u]; nVe[g] = aVe[u];
  }
}

// ---------------- fused graph attention + residual LN (KT=10, xe-writeback: proven best) ----------------
// R17 lesson: achieved occupancy is pinned ~40% regardless of LDS; keeping V in LDS
// (in-place over consumed hE rows) avoids the vvAll register spill (VGPR 60, no scratch).
template<bool ENC>
__global__ __launch_bounds__(H_) void attn_kernel(const float* __restrict__ hV_in,
    const float* __restrict__ hE, const int* __restrict__ E_idx, const float* __restrict__ mask,
    const float* __restrict__ WQ, const float* __restrict__ WK1,
    const float* __restrict__ WV1, const float* __restrict__ WO,
    const float* __restrict__ nKb, const float* __restrict__ nVb,
    const float* __restrict__ nKe, const float* __restrict__ nVe,
    float* __restrict__ hV_out) {
  constexpr int KT = 10;
  const int node = blockIdx.x;
  const int b = node / N_, n = node % N_;
  const int t = threadIdx.x;
  const int head = t >> 5, lane32 = t & 31;
  __shared__ __attribute__((aligned(16))) float x0[H_];
  __shared__ __attribute__((aligned(16))) float xe[K_ * H_];
  __shared__ __attribute__((aligned(16))) float ob[H_];
  __shared__ float sc[NH_ * K_];
  __shared__ float att[NH_ * K_];
  __shared__ float red[H_];
  __shared__ int nbs[K_];

  x0[t] = hV_in[(size_t)node * H_ + t];
  if (t < K_) nbs[t] = E_idx[node * K_ + t];
  {
    const float* src = hE + (size_t)node * K_ * H_;
    for (int i = t; i < K_ * H_; i += H_) xe[i] = src[i];
  }
  __syncthreads();

  float qreg = 0.f;
  for (int j4 = 0; j4 < H_ / 4; j4++) {
    float4 xv = ((const float4*)x0)[j4];
    int j = j4 * 4;
    qreg = fmaf(xv.x, WQ[(j + 0) * H_ + t],
           fmaf(xv.y, WQ[(j + 1) * H_ + t],
           fmaf(xv.z, WQ[(j + 2) * H_ + t],
           fmaf(xv.w, WQ[(j + 3) * H_ + t], qreg))));
  }
  float mi = mask[b * N_ + n];

  for (int kt = 0; kt < K_; kt += KT) {
    float kv[KT], vv[KT];
    #pragma unroll
    for (int u = 0; u < KT; u++) { kv[u] = 0.f; vv[u] = 0.f; }
    for (int j4 = 0; j4 < H_ / 4; j4++) {
      int j = j4 * 4;
      float wk0 = WK1[(j + 0) * H_ + t], wk1 = WK1[(j + 1) * H_ + t];
      float wk2 = WK1[(j + 2) * H_ + t], wk3 = WK1[(j + 3) * H_ + t];
      float wv0 = WV1[(j + 0) * H_ + t], wv1 = WV1[(j + 1) * H_ + t];
      float wv2 = WV1[(j + 2) * H_ + t], wv3 = WV1[(j + 3) * H_ + t];
      #pragma unroll
      for (int u = 0; u < KT; u++) {
        float4 xv = *((const float4*)(xe + (kt + u) * H_ + j));
        kv[u] = fmaf(xv.x, wk0, fmaf(xv.y, wk1, fmaf(xv.z, wk2, fmaf(xv.w, wk3, kv[u]))));
        vv[u] = fmaf(xv.x, wv0, fmaf(xv.y, wv1, fmaf(xv.z, wv2, fmaf(xv.w, wv3, vv[u]))));
      }
    }
    __syncthreads();
    #pragma unroll
    for (int u = 0; u < KT; u++) {
      int k = kt + u;
      int nb = nbs[k];
      size_t nbg = (size_t)(b * N_ + nb) * H_ + t;
      float kvt, vvt;
      if (ENC) {
        kvt = kv[u] + nKb[nbg];
        vvt = vv[u] + nVb[nbg];
      } else {
        float ar = (nb < n) ? 1.f : 0.f;
        float bw = mi * ar, fw = mi * (1.f - ar);
        kvt = fmaf(mi, kv[u], fmaf(bw, nKb[nbg], fw * nKe[nbg]));
        vvt = fmaf(mi, vv[u], fmaf(bw, nVb[nbg], fw * nVe[nbg]));
      }
      xe[k * H_ + t] = vvt;
      float prod = qreg * kvt;
      #pragma unroll
      for (int off = 16; off > 0; off >>= 1) prod += __shfl_xor(prod, off, 32);
      if (lane32 == 0) {
        float lg = prod * 0.17677669529663687f;  // 1/sqrt(32)
        if (ENC) {
          float m2 = mi * mask[b * N_ + nb];
          sc[head * K_ + k] = (m2 > 0.f) ? lg : NEG_INF_;
        } else {
          sc[head * K_ + k] = lg;
        }
      }
    }
  }
  __syncthreads();

  if (t < NH_) {
    float mx = -3.4e38f;
    for (int k = 0; k < K_; k++) mx = fmaxf(mx, sc[t * K_ + k]);
    float s = 0.f;
    for (int k = 0; k < K_; k++) { float ev = expf(sc[t * K_ + k] - mx); att[t * K_ + k] = ev; s += ev; }
    float inv = 1.f / s;
    for (int k = 0; k < K_; k++) att[t * K_ + k] *= inv;
  }
  __syncthreads();
  if (ENC && t < K_) {
    float m2 = mi * mask[b * N_ + nbs[t]];
    for (int hh = 0; hh < NH_; hh++) att[hh * K_ + t] *= m2;
  }
  __syncthreads();
  float o = 0.f;
  #pragma unroll
  for (int k = 0; k < K_; k++) o = fmaf(att[head * K_ + k], xe[k * H_ + t], o);
  ob[t] = o; __syncthreads();
  float dh = 0.f;
  for (int j4 = 0; j4 < H_ / 4; j4++) {
    float4 ov = ((const float4*)ob)[j4];
    int j = j4 * 4;
    dh = fmaf(ov.x, WO[(j + 0) * H_ + t],
         fmaf(ov.y, WO[(j + 1) * H_ + t],
         fmaf(ov.z, WO[(j + 2) * H_ + t],
         fmaf(ov.w, WO[(j + 3) * H_ + t], dh))));
  }
  float r = x0[t] + dh;
  float mean = block_sum128f(r, red) * (1.f / H_);
  float d0 = r - mean;
  float var = block_sum128f(d0 * d0, red) * (1.f / H_);
  hV_out[(size_t)node * H_ + t] = d0 * rsqrtf(var + 1e-6f);
}

// ---------------- FFN, FB=8 nodes/block: LN(x + relu(x@W1+b1)@W2+b2) * mask ----------------
constexpr int FB_ = 8;
__global__ __launch_bounds__(H_) void ffn_kernel(float* __restrict__ hV, const float* __restrict__ mask,
    const float* __restrict__ W1, const float* __restrict__ b1,
    const float* __restrict__ W2, const float* __restrict__ b2) {
  int n0 = blockIdx.x * FB_, t = threadIdx.x;
  __shared__ __attribute__((aligned(16))) float x[FB_ * H_];
  __shared__ __attribute__((aligned(16))) float hid[FB_ * 4 * H_];
  __shared__ float mstat[FB_], istat[FB_];
  #pragma unroll
  for (int u = 0; u < FB_; u++) x[u * H_ + t] = hV[(size_t)(n0 + u) * H_ + t];
  __syncthreads();
  for (int c = 0; c < 4; c++) {
    float acc[FB_];
    float b0 = b1[c * H_ + t];
    #pragma unroll
    for (int u = 0; u < FB_; u++) acc[u] = b0;
    for (int h4 = 0; h4 < H_ / 4; h4++) {
      int h = h4 * 4;
      float w0 = W1[(h + 0) * 4 * H_ + c * H_ + t];
      float w1 = W1[(h + 1) * 4 * H_ + c * H_ + t];
      float w2 = W1[(h + 2) * 4 * H_ + c * H_ + t];
      float w3 = W1[(h + 3) * 4 * H_ + c * H_ + t];
      #pragma unroll
      for (int u = 0; u < FB_; u++) {
        float4 xv = ((const float4*)(x + u * H_))[h4];
        acc[u] = fmaf(xv.x, w0, fmaf(xv.y, w1, fmaf(xv.z, w2, fmaf(xv.w, w3, acc[u]))));
      }
    }
    #pragma unroll
    for (int u = 0; u < FB_; u++) hid[u * 4 * H_ + c * H_ + t] = fmaxf(acc[u], 0.f);
  }
  __syncthreads();
  float o[FB_];
  {
    float b0 = b2[t];
    #pragma unroll
    for (int u = 0; u < FB_; u++) o[u] = b0;
  }
  for (int j4 = 0; j4 < (4 * H_) / 4; j4++) {
    int j = j4 * 4;
    float w0 = W2[(j + 0) * H_ + t], w1 = W2[(j + 1) * H_ + t];
    float w2 = W2[(j + 2) * H_ + t], w3 = W2[(j + 3) * H_ + t];
    #pragma unroll
    for (int u = 0; u < FB_; u++) {
      float4 hv = ((const float4*)(hid + u * 4 * H_))[j4];
      o[u] = fmaf(hv.x, w0, fmaf(hv.y, w1, fmaf(hv.z, w2, fmaf(hv.w, w3, o[u]))));
    }
  }
  float r[FB_];
  #pragma unroll
  for (int u = 0; u < FB_; u++) r[u] = x[u * H_ + t] + o[u];
  __syncthreads();
  #pragma unroll
  for (int u = 0; u < FB_; u++) x[u * H_ + t] = r[u];
  __syncthreads();
  if (t < FB_) {
    float s = 0.f;
    for (int j0 = 0; j0 < H_; j0++) {
      int j = (j0 + t * 2) & (H_ - 1);
      s += x[t * H_ + j];
    }
    float mean = s * (1.f / H_);
    float vs = 0.f;
    for (int j0 = 0; j0 < H_; j0++) {
      int j = (j0 + t * 2) & (H_ - 1);
      float d = x[t * H_ + j] - mean;
      vs = fmaf(d, d, vs);
    }
    mstat[t] = mean;
    istat[t] = rsqrtf(vs * (1.f / H_) + 1e-6f);
  }
  __syncthreads();
  #pragma unroll
  for (int u = 0; u < FB_; u++) {
    float y = (r[u] - mstat[u]) * istat[u];
    y *= mask[n0 + u];
    hV[(size_t)(n0 + u) * H_ + t] = y;
  }
}

// ---------------- output: log_softmax(hV @ W_out + b_out), fp32, 2 nodes/block ----------------
__global__ __launch_bounds__(128) void out_kernel(const float* __restrict__ hV,
    const float* __restrict__ Wout, const float* __restrict__ bout, float* __restrict__ out) {
  int g = threadIdx.x >> 6, t = threadIdx.x & 63;
  int node = blockIdx.x * 2 + g;
  __shared__ float x[2][H_];
  __shared__ float lg[2][V_];
  __shared__ float lse[2];
  x[g][t] = hV[(size_t)node * H_ + t];
  x[g][t + 64] = hV[(size_t)node * H_ + t + 64];
  __syncthreads();
  if (t < V_) {
    float a = bout[t];
    for (int h = 0; h < H_; h++) a = fmaf(x[g][h], Wout[h * V_ + t], a);
    lg[g][t] = a;
  }
  __syncthreads();
  if (t == 0) {
    float mx = -3.4e38f;
    for (int v = 0; v < V_; v++) mx = fmaxf(mx, lg[g][v]);
    float s = 0.f;
    for (int v = 0; v < V_; v++) s += expf(lg[g][v] - mx);
    lse[g] = mx + logf(s);
  }
  __syncthreads();
  if (t < V_) out[(size_t)node * V_ + t] = lg[g][t] - lse[g];
}

// ---------------- host ----------------
extern "C" void kernel_launch(void* const* d_in, const int* in_sizes, int n_in,
                              void* d_out, int out_size, void* d_ws, size_t ws_size,
                              hipStream_t stream) {
  const float* X    = (const float*)d_in[0];
  const float* mask = (const float*)d_in[1];
  const int*   S    = (const int*)d_in[2];
  const float* Wfn  = (const float*)d_in[3];
  const float* bfn  = (const float*)d_in[4];
  const float* Wfe  = (const float*)d_in[5];
  const float* bfe  = (const float*)d_in[6];
  const float* Wv   = (const float*)d_in[7];
  const float* bv   = (const float*)d_in[8];
  const float* We   = (const float*)d_in[9];
  const float* be   = (const float*)d_in[10];
  const float* Ws   = (const float*)d_in[11];
  const float* eWQ  = (const float*)d_in[12];
  const float* eWK  = (const float*)d_in[13];
  const float* eWV  = (const float*)d_in[14];
  const float* eWO  = (const float*)d_in[15];
  const float* eW1  = (const float*)d_in[16];
  const float* eb1  = (const float*)d_in[17];
  const float* eW2  = (const float*)d_in[18];
  const float* eb2  = (const float*)d_in[19];
  const float* dWQ  = (const float*)d_in[20];
  const float* dWK  = (const float*)d_in[21];
  const float* dWV  = (const float*)d_in[22];
  const float* dWO  = (const float*)d_in[23];
  const float* dW1  = (const float*)d_in[24];
  const float* db1  = (const float*)d_in[25];
  const float* dW2  = (const float*)d_in[26];
  const float* db2  = (const float*)d_in[27];
  const float* Wout = (const float*)d_in[28];
  const float* bout = (const float*)d_in[29];
  float* out = (float*)d_out;

  char* w = (char*)d_ws;
  int*    eidx = (int*)w;     w += (size_t)BN_ * K_ * 4;
  float*  dnb  = (float*)w;   w += (size_t)BN_ * K_ * 4;
  float*  vf   = (float*)w;   w += (size_t)BN_ * 6 * 4;
  float*  hVa  = (float*)w;   w += (size_t)BN_ * H_ * 4;
  float*  hVb  = (float*)w;   w += (size_t)BN_ * H_ * 4;
  float*  hVc  = (float*)w;   w += (size_t)BN_ * H_ * 4;
  float*  nKb  = (float*)w;   w += (size_t)BN_ * H_ * 4;
  float*  nVb  = (float*)w;   w += (size_t)BN_ * H_ * 4;
  float*  nKe  = (float*)w;   w += (size_t)BN_ * H_ * 4;
  float*  nVe  = (float*)w;   w += (size_t)BN_ * H_ * 4;
  float*  hE   = (float*)w;   w += (size_t)BN_ * K_ * H_ * 4;

  topk_kernel<<<BN_, 256, 0, stream>>>(X, mask, eidx, dnb);
  dihedral_kernel<<<(BN_ + 255) / 256, 256, 0, stream>>>(X, vf);
  node_embed_kernel<<<BN_, H_, 0, stream>>>(vf, Wfn, bfn, Wv, bv, hVa);
  edge_embed_kernel<<<BN_ * K_ / EB_, H_, 0, stream>>>(eidx, dnb, Wfe, bfe, We, be, hE);

  // encoder: a->b, b->a, a->b
  float* cur = hVa; float* nxt = hVb;
  for (int l = 0; l < 3; l++) {
    const float* WK = eWK + (size_t)l * 2 * H_ * H_;
    const float* WV = eWV + (size_t)l * 2 * H_ * H_;
    node_proj_kernel<<<BN_ / 16, H_, 0, stream>>>(cur,
        WK + (size_t)H_ * H_, WV + (size_t)H_ * H_, nKb, nVb);
    attn_kernel<true><<<BN_, H_, 0, stream>>>(cur, hE, eidx, mask,
        eWQ + (size_t)l * H_ * H_, WK, WV, eWO + (size_t)l * H_ * H_,
        nKb, nVb, nullptr, nullptr, nxt);
    ffn_kernel<<<BN_ / FB_, H_, 0, stream>>>(nxt, mask,
        eW1 + (size_t)l * H_ * 4 * H_, eb1 + (size_t)l * 4 * H_,
        eW2 + (size_t)l * 4 * H_ * H_, eb2 + (size_t)l * H_);
    float* tmp = cur; cur = nxt; nxt = tmp;
  }
  float* henc = cur;  // = hVb
  // decoder: henc->a, a->c, c->a (henc preserved)
  float* din = henc;
  float* douts[3] = { hVa, hVc, hVa };
  for (int l = 0; l < 3; l++) {
    const float* WK = dWK + (size_t)l * 3 * H_ * H_;
    const float* WV = dWV + (size_t)l * 3 * H_ * H_;
    node_proj3_kernel<<<BN_ / 8, H_, 0, stream>>>(S, Ws, din, henc,
        WK + (size_t)H_ * H_, WV + (size_t)H_ * H_,
        WK + (size_t)2 * H_ * H_, WV + (size_t)2 * H_ * H_,
        nKb, nVb, nKe, nVe);
    attn_kernel<false><<<BN_, H_, 0, stream>>>(din, hE, eidx, mask,
        dWQ + (size_t)l * H_ * H_, WK, WV, dWO + (size_t)l * H_ * H_,
        nKb, nVb, nKe, nVe, douts[l]);
    ffn_kernel<<<BN_ / FB_, H_, 0, stream>>>(douts[l], mask,
        dW1 + (size_t)l * H_ * 4 * H_, db1 + (size_t)l * 4 * H_,
        dW2 + (size_t)l * 4 * H_ * H_, db2 + (size_t)l * H_);
    din = douts[l];
  }
  out_kernel<<<BN_ / 2, 128, 0, stream>>>(din, Wout, bout, out);
}

// Round 19
// 3340.189 us; speedup vs baseline: 1.0748x; 1.0357x over previous
//
#include <hip/hip_runtime.h>
#include <hip/hip_bf16.h>
#include <math.h>

#define DEVFN __device__ __forceinline__

constexpr int B_ = 16, N_ = 512, K_ = 30, H_ = 128;
constexpr int NH_ = 4, V_ = 20;
constexpr int BN_ = B_ * N_;
constexpr float NEG_INF_ = -3.4028235e38f;

DEVFN float block_sum128f(float v, float* sbuf) {
  int t = threadIdx.x;
  sbuf[t] = v; __syncthreads();
  #pragma unroll
  for (int s = 64; s > 0; s >>= 1) {
    if (t < s) sbuf[t] += sbuf[t + s];
    __syncthreads();
  }
  float r = sbuf[0];
  __syncthreads();
  return r;
}

// ---------------- top-K neighbors: distances BIT-EXACT to plain numpy float32 ----------------
// DO NOT TOUCH: bit-exact __f*_rn distance + higher-index tie-break matches the np
// reference at exact ties (bf16-valued coords) — R8 fix. Tree reduction (measured
// faster than shfl-butterfly variant: 3343 vs 3405+ total).
__global__ __launch_bounds__(256) void topk_kernel(const float* __restrict__ X,
    const float* __restrict__ mask, int* __restrict__ E_idx, float* __restrict__ Dnb) {
  __shared__ float xs[N_ * 3];
  __shared__ float ds[N_];
  __shared__ float fred[256];
  __shared__ unsigned long long kred[256];
  int b = blockIdx.x / N_, i = blockIdx.x % N_;
  int t = threadIdx.x;
  for (int j = t; j < N_; j += 256) {
    const float* p = X + ((size_t)(b * N_ + j) * 4 + 1) * 3;  // CA atom
    xs[j * 3 + 0] = p[0]; xs[j * 3 + 1] = p[1]; xs[j * 3 + 2] = p[2];
  }
  __syncthreads();
  float xi0 = xs[i * 3], xi1 = xs[i * 3 + 1], xi2 = xs[i * 3 + 2];
  float mi = mask[b * N_ + i];
  float lmax = -3.4e38f;
  for (int j = t; j < N_; j += 256) {
    float dx = __fsub_rn(xi0, xs[j * 3]);
    float dy = __fsub_rn(xi1, xs[j * 3 + 1]);
    float dz = __fsub_rn(xi2, xs[j * 3 + 2]);
    float m2 = __fmul_rn(mi, mask[b * N_ + j]);
    float s = __fadd_rn(__fadd_rn(__fadd_rn(__fmul_rn(dx, dx), __fmul_rn(dy, dy)),
                                  __fmul_rn(dz, dz)), 1e-6f);
    float D = __fmul_rn(m2, __fsqrt_rn(s));
    ds[j] = D;
    lmax = fmaxf(lmax, D);
  }
  fred[t] = lmax; __syncthreads();
  for (int s = 128; s > 0; s >>= 1) { if (t < s) fred[t] = fmaxf(fred[t], fred[t + s]); __syncthreads(); }
  float Dmax = fred[0]; __syncthreads();
  for (int j = t; j < N_; j += 256) {
    float m2 = __fmul_rn(mi, mask[b * N_ + j]);
    ds[j] = __fadd_rn(ds[j], __fmul_rn(__fsub_rn(1.f, m2), Dmax));
  }
  __syncthreads();
  // extract K smallest; equal distances -> HIGHER index first
  for (int kk = 0; kk < K_; kk++) {
    unsigned long long best = ~0ull;
    for (int j = t; j < N_; j += 256) {
      unsigned long long key = (((unsigned long long)__float_as_uint(ds[j])) << 32)
                             | (unsigned)(N_ - 1 - j);
      if (key < best) best = key;
    }
    kred[t] = best; __syncthreads();
    for (int s = 128; s > 0; s >>= 1) { if (t < s && kred[t + s] < kred[t]) kred[t] = kred[t + s]; __syncthreads(); }
    if (t == 0) {
      unsigned long long k0 = kred[0];
      int j = N_ - 1 - (int)(k0 & 0xffffffffull);
      E_idx[blockIdx.x * K_ + kk] = j;
      Dnb[blockIdx.x * K_ + kk] = __uint_as_float((unsigned)(k0 >> 32));
      ds[j] = 3.4028235e38f;
    }
    __syncthreads();
  }
}

// ---------------- dihedral features (1 thread / node), fp32 ----------------
DEVFN void load_atom(const float* X, int b, int m, float* p) {
  const float* q = X + ((size_t)(b * N_ + m / 3) * 4 + (m % 3)) * 3;
  p[0] = q[0]; p[1] = q[1]; p[2] = q[2];
}
DEVFN void cross3(const float* a, const float* b, float* c) {
  c[0] = a[1] * b[2] - a[2] * b[1];
  c[1] = a[2] * b[0] - a[0] * b[2];
  c[2] = a[0] * b[1] - a[1] * b[0];
}
DEVFN void norm3(float* v) {
  float n = sqrtf(v[0] * v[0] + v[1] * v[1] + v[2] * v[2]) + 1e-7f;
  v[0] /= n; v[1] /= n; v[2] /= n;
}
__global__ __launch_bounds__(256) void dihedral_kernel(const float* __restrict__ X, float* __restrict__ Vf) {
  int idx = blockIdx.x * blockDim.x + threadIdx.x;
  if (idx >= BN_) return;
  int b = idx / N_, n = idx % N_;
  float cs[3], sn[3];
  for (int s = 0; s < 3; s++) {
    int p = 3 * n + s;
    float a = 0.f;
    if (p >= 1 && p <= 3 * N_ - 3) {
      int tt = p - 1;
      float u[3][3], prev[3], cur[3];
      load_atom(X, b, tt, prev);
      for (int q = 0; q < 3; q++) {
        load_atom(X, b, tt + q + 1, cur);
        float d0 = cur[0] - prev[0], d1 = cur[1] - prev[1], d2 = cur[2] - prev[2];
        float nr = sqrtf(d0 * d0 + d1 * d1 + d2 * d2) + 1e-7f;
        u[q][0] = d0 / nr; u[q][1] = d1 / nr; u[q][2] = d2 / nr;
        prev[0] = cur[0]; prev[1] = cur[1]; prev[2] = cur[2];
      }
      float n2v[3], n1v[3];
      cross3(u[0], u[1], n2v); norm3(n2v);
      cross3(u[1], u[2], n1v); norm3(n1v);
      float cd = n2v[0] * n1v[0] + n2v[1] * n1v[1] + n2v[2] * n1v[2];
      cd = fminf(fmaxf(cd, -1.f + 1e-7f), 1.f - 1e-7f);
      float dt = u[0][0] * n1v[0] + u[0][1] * n1v[1] + u[0][2] * n1v[2];
      float sg = (dt > 0.f) ? 1.f : ((dt < 0.f) ? -1.f : 0.f);
      a = sg * acosf(cd);
    }
    cs[s] = cosf(a); sn[s] = sinf(a);
  }
  float* o = Vf + (size_t)idx * 6;
  o[0] = cs[0]; o[1] = cs[1]; o[2] = cs[2]; o[3] = sn[0]; o[4] = sn[1]; o[5] = sn[2];
}

// ---------------- node embed: hV = LN(V@Wfn+bfn) @ Wv + bv (fp32) ----------------
__global__ __launch_bounds__(H_) void node_embed_kernel(const float* __restrict__ Vf,
    const float* __restrict__ Wfn, const float* __restrict__ bfn,
    const float* __restrict__ Wv, const float* __restrict__ bv, float* __restrict__ hV) {
  int node = blockIdx.x, t = threadIdx.x;
  __shared__ float v6[6];
  __shared__ float t1[H_];
  __shared__ float red[H_];
  if (t < 6) v6[t] = Vf[(size_t)node * 6 + t];
  __syncthreads();
  float acc = bfn[t];
  for (int f = 0; f < 6; f++) acc = fmaf(v6[f], Wfn[f * H_ + t], acc);
  float mean = block_sum128f(acc, red) * (1.f / H_);
  float d0 = acc - mean;
  float var = block_sum128f(d0 * d0, red) * (1.f / H_);
  t1[t] = d0 * rsqrtf(var + 1e-6f);
  __syncthreads();
  float o = bv[t];
  for (int j = 0; j < H_; j++) o = fmaf(t1[j], Wv[j * H_ + t], o);
  hV[(size_t)node * H_ + t] = o;
}

// ---------------- edge embed, EB=16 edges/block: hE = LN(E@Wfe+bfe) @ We + be ----------------
constexpr int EB_ = 16;
__global__ __launch_bounds__(H_) void edge_embed_kernel(const int* __restrict__ E_idx,
    const float* __restrict__ Dnb, const float* __restrict__ Wfe, const float* __restrict__ bfe,
    const float* __restrict__ We, const float* __restrict__ be, float* __restrict__ hE) {
  int e0 = blockIdx.x * EB_, t = threadIdx.x;
  __shared__ float feats[EB_ * 32];
  __shared__ __attribute__((aligned(16))) float buf[EB_ * H_];
  __shared__ float mstat[EB_], istat[EB_];
  #pragma unroll
  for (int p = 0; p < 4; p++) {
    int u = p * 4 + (t >> 5);
    int f = t & 31;
    int e = e0 + u;
    int n = (e / K_) % N_;
    float v;
    if (f < 16) {
      int jj = (f < 8) ? f : (f - 8);
      float freq = expf(-logf(10000.f) * (2.f * jj) / 16.f);
      float ang = (float)(E_idx[e] - n) * freq;
      v = (f < 8) ? cosf(ang) : sinf(ang);
    } else {
      int r = f - 16;
      float mu = 20.f * (float)r / 15.f;
      float z = (Dnb[e] - mu) * (1.f / 1.25f);
      v = expf(-z * z);
    }
    feats[u * 32 + f] = v;
  }
  __syncthreads();
  float acc[EB_];
  {
    float b0 = bfe[t];
    #pragma unroll
    for (int u = 0; u < EB_; u++) acc[u] = b0;
  }
  for (int f = 0; f < 32; f++) {
    float wv = Wfe[f * H_ + t];
    #pragma unroll
    for (int u = 0; u < EB_; u++) acc[u] = fmaf(feats[u * 32 + f], wv, acc[u]);
  }
  #pragma unroll
  for (int u = 0; u < EB_; u++) buf[u * H_ + t] = acc[u];
  __syncthreads();
  if (t < EB_) {
    float s = 0.f;
    for (int j0 = 0; j0 < H_; j0++) {
      int j = (j0 + t * 2) & (H_ - 1);
      s += buf[t * H_ + j];
    }
    float mean = s * (1.f / H_);
    float vs = 0.f;
    for (int j0 = 0; j0 < H_; j0++) {
      int j = (j0 + t * 2) & (H_ - 1);
      float d = buf[t * H_ + j] - mean;
      vs = fmaf(d, d, vs);
    }
    mstat[t] = mean;
    istat[t] = rsqrtf(vs * (1.f / H_) + 1e-6f);
  }
  __syncthreads();
  #pragma unroll
  for (int u = 0; u < EB_; u++) buf[u * H_ + t] = (acc[u] - mstat[u]) * istat[u];
  __syncthreads();
  float o[EB_];
  {
    float b0 = be[t];
    #pragma unroll
    for (int u = 0; u < EB_; u++) o[u] = b0;
  }
  for (int j4 = 0; j4 < H_ / 4; j4++) {
    int j = j4 * 4;
    float w0 = We[(j + 0) * H_ + t], w1 = We[(j + 1) * H_ + t];
    float w2 = We[(j + 2) * H_ + t], w3 = We[(j + 3) * H_ + t];
    #pragma unroll
    for (int u = 0; u < EB_; u++) {
      float4 xv = ((const float4*)(buf + u * H_))[j4];
      o[u] = fmaf(xv.x, w0, fmaf(xv.y, w1, fmaf(xv.z, w2, fmaf(xv.w, w3, o[u]))));
    }
  }
  #pragma unroll
  for (int u = 0; u < EB_; u++) hE[(size_t)(e0 + u) * H_ + t] = o[u];
}

// ---------------- per-node projection (encoder): oa/ob = x@Wa/Wb ----------------
__global__ __launch_bounds__(128) void node_proj_kernel(const float* __restrict__ x1,
    const float* __restrict__ Wa1, const float* __restrict__ Wb1,
    float* __restrict__ oa, float* __restrict__ ob) {
  constexpr int NT = 16;
  int n0 = blockIdx.x * NT, t = threadIdx.x;
  __shared__ __attribute__((aligned(16))) float xs1[NT * H_];
  #pragma unroll
  for (int u = 0; u < NT; u++) xs1[u * H_ + t] = x1[(size_t)(n0 + u) * H_ + t];
  __syncthreads();
  float aa[NT], ab[NT];
  #pragma unroll
  for (int u = 0; u < NT; u++) { aa[u] = 0.f; ab[u] = 0.f; }
  for (int j4 = 0; j4 < H_ / 4; j4++) {
    int j = j4 * 4;
    float wa0 = Wa1[(j + 0) * H_ + t], wa1 = Wa1[(j + 1) * H_ + t];
    float wa2 = Wa1[(j + 2) * H_ + t], wa3 = Wa1[(j + 3) * H_ + t];
    float wb0 = Wb1[(j + 0) * H_ + t], wb1 = Wb1[(j + 1) * H_ + t];
    float wb2 = Wb1[(j + 2) * H_ + t], wb3 = Wb1[(j + 3) * H_ + t];
    #pragma unroll
    for (int u = 0; u < NT; u++) {
      float4 xv = ((const float4*)(xs1 + u * H_))[j4];
      aa[u] = fmaf(xv.x, wa0, fmaf(xv.y, wa1, fmaf(xv.z, wa2, fmaf(xv.w, wa3, aa[u]))));
      ab[u] = fmaf(xv.x, wb0, fmaf(xv.y, wb1, fmaf(xv.z, wb2, fmaf(xv.w, wb3, ab[u]))));
    }
  }
  #pragma unroll
  for (int u = 0; u < NT; u++) {
    oa[(size_t)(n0 + u) * H_ + t] = aa[u];
    ob[(size_t)(n0 + u) * H_ + t] = ab[u];
  }
}

// ---------------- decoder fused projection: nKb/nVb = Ws[S]@WK2/WV2 + din@WK3/WV3 ;
//                  nKe/nVe = henc@WK3/WV3.  Ws gather inline; WK3/WV3 streamed once.
__global__ __launch_bounds__(128) void node_proj3_kernel(const int* __restrict__ S,
    const float* __restrict__ Ws, const float* __restrict__ din, const float* __restrict__ henc,
    const float* __restrict__ WK2, const float* __restrict__ WV2,
    const float* __restrict__ WK3, const float* __restrict__ WV3,
    float* __restrict__ nKb, float* __restrict__ nVb,
    float* __restrict__ nKe, float* __restrict__ nVe) {
  constexpr int NT = 8;
  int n0 = blockIdx.x * NT, t = threadIdx.x;
  __shared__ __attribute__((aligned(16))) float xs1[NT * H_];  // hS
  __shared__ __attribute__((aligned(16))) float xs2[NT * H_];  // din
  __shared__ __attribute__((aligned(16))) float xs3[NT * H_];  // henc
  #pragma unroll
  for (int u = 0; u < NT; u++) {
    int node = n0 + u;
    xs1[u * H_ + t] = Ws[(size_t)S[node] * H_ + t];
    xs2[u * H_ + t] = din[(size_t)node * H_ + t];
    xs3[u * H_ + t] = henc[(size_t)node * H_ + t];
  }
  __syncthreads();
  float aKb[NT], aVb[NT], aKe[NT], aVe[NT];
  #pragma unroll
  for (int u = 0; u < NT; u++) { aKb[u] = 0.f; aVb[u] = 0.f; aKe[u] = 0.f; aVe[u] = 0.f; }
  for (int j4 = 0; j4 < H_ / 4; j4++) {
    int j = j4 * 4;
    float k20 = WK2[(j + 0) * H_ + t], k21 = WK2[(j + 1) * H_ + t];
    float k22 = WK2[(j + 2) * H_ + t], k23 = WK2[(j + 3) * H_ + t];
    float v20 = WV2[(j + 0) * H_ + t], v21 = WV2[(j + 1) * H_ + t];
    float v22 = WV2[(j + 2) * H_ + t], v23 = WV2[(j + 3) * H_ + t];
    float k30 = WK3[(j + 0) * H_ + t], k31 = WK3[(j + 1) * H_ + t];
    float k32 = WK3[(j + 2) * H_ + t], k33 = WK3[(j + 3) * H_ + t];
    float v30 = WV3[(j + 0) * H_ + t], v31 = WV3[(j + 1) * H_ + t];
    float v32 = WV3[(j + 2) * H_ + t], v33 = WV3[(j + 3) * H_ + t];
    #pragma unroll
    for (int u = 0; u < NT; u++) {
      float4 a = ((const float4*)(xs1 + u * H_))[j4];
      float4 b = ((const float4*)(xs2 + u * H_))[j4];
      float4 c = ((const float4*)(xs3 + u * H_))[j4];
      aKb[u] = fmaf(a.x, k20, fmaf(a.y, k21, fmaf(a.z, k22, fmaf(a.w, k23, aKb[u]))));
      aKb[u] = fmaf(b.x, k30, fmaf(b.y, k31, fmaf(b.z, k32, fmaf(b.w, k33, aKb[u]))));
      aVb[u] = fmaf(a.x, v20, fmaf(a.y, v21, fmaf(a.z, v22, fmaf(a.w, v23, aVb[u]))));
      aVb[u] = fmaf(b.x, v30, fmaf(b.y, v31, fmaf(b.z, v32, fmaf(b.w, v33, aVb[u]))));
      aKe[u] = fmaf(c.x, k30, fmaf(c.y, k31, fmaf(c.z, k32, fmaf(c.w, k33, aKe[u]))));
      aVe[u] = fmaf(c.x, v30, fmaf(c.y, v31, fmaf(c.z, v32, fmaf(c.w, v33, aVe[u]))));
    }
  }
  #pragma unroll
  for (int u = 0; u < NT; u++) {
    size_t g = (size_t)(n0 + u) * H_ + t;
    nKb[g] = aKb[u]; nVb[g] = aVb[u]; nKe[g] = aKe[u]; nVe[g] = aVe[u];
  }
}

// ---------------- fused graph attention + residual LN (KT=10, xe-writeback: proven best) ----------------
template<bool ENC>
__global__ __launch_bounds__(H_) void attn_kernel(const float* __restrict__ hV_in,
    const float* __restrict__ hE, const int* __restrict__ E_idx, const float* __restrict__ mask,
    const float* __restrict__ WQ, const float* __restrict__ WK1,
    const float* __restrict__ WV1, const float* __restrict__ WO,
    const float* __restrict__ nKb, const float* __restrict__ nVb,
    const float* __restrict__ nKe, const float* __restrict__ nVe,
    float* __restrict__ hV_out) {
  constexpr int KT = 10;
  const int node = blockIdx.x;
  const int b = node / N_, n = node % N_;
  const int t = threadIdx.x;
  const int head = t >> 5, lane32 = t & 31;
  __shared__ __attribute__((aligned(16))) float x0[H_];
  __shared__ __attribute__((aligned(16))) float xe[K_ * H_];
  __shared__ __attribute__((aligned(16))) float ob[H_];
  __shared__ float sc[NH_ * K_];
  __shared__ float att[NH_ * K_];
  __shared__ float red[H_];
  __shared__ int nbs[K_];

  x0[t] = hV_in[(size_t)node * H_ + t];
  if (t < K_) nbs[t] = E_idx[node * K_ + t];
  {
    const float* src = hE + (size_t)node * K_ * H_;
    for (int i = t; i < K_ * H_; i += H_) xe[i] = src[i];
  }
  __syncthreads();

  float qreg = 0.f;
  for (int j4 = 0; j4 < H_ / 4; j4++) {
    float4 xv = ((const float4*)x0)[j4];
    int j = j4 * 4;
    qreg = fmaf(xv.x, WQ[(j + 0) * H_ + t],
           fmaf(xv.y, WQ[(j + 1) * H_ + t],
           fmaf(xv.z, WQ[(j + 2) * H_ + t],
           fmaf(xv.w, WQ[(j + 3) * H_ + t], qreg))));
  }
  float mi = mask[b * N_ + n];

  for (int kt = 0; kt < K_; kt += KT) {
    float kv[KT], vv[KT];
    #pragma unroll
    for (int u = 0; u < KT; u++) { kv[u] = 0.f; vv[u] = 0.f; }
    for (int j4 = 0; j4 < H_ / 4; j4++) {
      int j = j4 * 4;
      float wk0 = WK1[(j + 0) * H_ + t], wk1 = WK1[(j + 1) * H_ + t];
      float wk2 = WK1[(j + 2) * H_ + t], wk3 = WK1[(j + 3) * H_ + t];
      float wv0 = WV1[(j + 0) * H_ + t], wv1 = WV1[(j + 1) * H_ + t];
      float wv2 = WV1[(j + 2) * H_ + t], wv3 = WV1[(j + 3) * H_ + t];
      #pragma unroll
      for (int u = 0; u < KT; u++) {
        float4 xv = *((const float4*)(xe + (kt + u) * H_ + j));
        kv[u] = fmaf(xv.x, wk0, fmaf(xv.y, wk1, fmaf(xv.z, wk2, fmaf(xv.w, wk3, kv[u]))));
        vv[u] = fmaf(xv.x, wv0, fmaf(xv.y, wv1, fmaf(xv.z, wv2, fmaf(xv.w, wv3, vv[u]))));
      }
    }
    __syncthreads();
    #pragma unroll
    for (int u = 0; u < KT; u++) {
      int k = kt + u;
      int nb = nbs[k];
      size_t nbg = (size_t)(b * N_ + nb) * H_ + t;
      float kvt, vvt;
      if (ENC) {
        kvt = kv[u] + nKb[nbg];
        vvt = vv[u] + nVb[nbg];
      } else {
        float ar = (nb < n) ? 1.f : 0.f;
        float bw = mi * ar, fw = mi * (1.f - ar);
        kvt = fmaf(mi, kv[u], fmaf(bw, nKb[nbg], fw * nKe[nbg]));
        vvt = fmaf(mi, vv[u], fmaf(bw, nVb[nbg], fw * nVe[nbg]));
      }
      xe[k * H_ + t] = vvt;
      float prod = qreg * kvt;
      #pragma unroll
      for (int off = 16; off > 0; off >>= 1) prod += __shfl_xor(prod, off, 32);
      if (lane32 == 0) {
        float lg = prod * 0.17677669529663687f;  // 1/sqrt(32)
        if (ENC) {
          float m2 = mi * mask[b * N_ + nb];
          sc[head * K_ + k] = (m2 > 0.f) ? lg : NEG_INF_;
        } else {
          sc[head * K_ + k] = lg;
        }
      }
    }
  }
  __syncthreads();

  if (t < NH_) {
    float mx = -3.4e38f;
    for (int k = 0; k < K_; k++) mx = fmaxf(mx, sc[t * K_ + k]);
    float s = 0.f;
    for (int k = 0; k < K_; k++) { float ev = expf(sc[t * K_ + k] - mx); att[t * K_ + k] = ev; s += ev; }
    float inv = 1.f / s;
    for (int k = 0; k < K_; k++) att[t * K_ + k] *= inv;
  }
  __syncthreads();
  if (ENC && t < K_) {
    float m2 = mi * mask[b * N_ + nbs[t]];
    for (int hh = 0; hh < NH_; hh++) att[hh * K_ + t] *= m2;
  }
  __syncthreads();
  float o = 0.f;
  #pragma unroll
  for (int k = 0; k < K_; k++) o = fmaf(att[head * K_ + k], xe[k * H_ + t], o);
  ob[t] = o; __syncthreads();
  float dh = 0.f;
  for (int j4 = 0; j4 < H_ / 4; j4++) {
    float4 ov = ((const float4*)ob)[j4];
    int j = j4 * 4;
    dh = fmaf(ov.x, WO[(j + 0) * H_ + t],
         fmaf(ov.y, WO[(j + 1) * H_ + t],
         fmaf(ov.z, WO[(j + 2) * H_ + t],
         fmaf(ov.w, WO[(j + 3) * H_ + t], dh))));
  }
  float r = x0[t] + dh;
  float mean = block_sum128f(r, red) * (1.f / H_);
  float d0 = r - mean;
  float var = block_sum128f(d0 * d0, red) * (1.f / H_);
  hV_out[(size_t)node * H_ + t] = d0 * rsqrtf(var + 1e-6f);
}

// ---------------- FFN, FB=8 nodes/block: LN(x + relu(x@W1+b1)@W2+b2) * mask ----------------
constexpr int FB_ = 8;
__global__ __launch_bounds__(H_) void ffn_kernel(float* __restrict__ hV, const float* __restrict__ mask,
    const float* __restrict__ W1, const float* __restrict__ b1,
    const float* __restrict__ W2, const float* __restrict__ b2) {
  int n0 = blockIdx.x * FB_, t = threadIdx.x;
  __shared__ __attribute__((aligned(16))) float x[FB_ * H_];
  __shared__ __attribute__((aligned(16))) float hid[FB_ * 4 * H_];
  __shared__ float mstat[FB_], istat[FB_];
  #pragma unroll
  for (int u = 0; u < FB_; u++) x[u * H_ + t] = hV[(size_t)(n0 + u) * H_ + t];
  __syncthreads();
  for (int c = 0; c < 4; c++) {
    float acc[FB_];
    float b0 = b1[c * H_ + t];
    #pragma unroll
    for (int u = 0; u < FB_; u++) acc[u] = b0;
    for (int h4 = 0; h4 < H_ / 4; h4++) {
      int h = h4 * 4;
      float w0 = W1[(h + 0) * 4 * H_ + c * H_ + t];
      float w1 = W1[(h + 1) * 4 * H_ + c * H_ + t];
      float w2 = W1[(h + 2) * 4 * H_ + c * H_ + t];
      float w3 = W1[(h + 3) * 4 * H_ + c * H_ + t];
      #pragma unroll
      for (int u = 0; u < FB_; u++) {
        float4 xv = ((const float4*)(x + u * H_))[h4];
        acc[u] = fmaf(xv.x, w0, fmaf(xv.y, w1, fmaf(xv.z, w2, fmaf(xv.w, w3, acc[u]))));
      }
    }
    #pragma unroll
    for (int u = 0; u < FB_; u++) hid[u * 4 * H_ + c * H_ + t] = fmaxf(acc[u], 0.f);
  }
  __syncthreads();
  float o[FB_];
  {
    float b0 = b2[t];
    #pragma unroll
    for (int u = 0; u < FB_; u++) o[u] = b0;
  }
  for (int j4 = 0; j4 < (4 * H_) / 4; j4++) {
    int j = j4 * 4;
    float w0 = W2[(j + 0) * H_ + t], w1 = W2[(j + 1) * H_ + t];
    float w2 = W2[(j + 2) * H_ + t], w3 = W2[(j + 3) * H_ + t];
    #pragma unroll
    for (int u = 0; u < FB_; u++) {
      float4 hv = ((const float4*)(hid + u * 4 * H_))[j4];
      o[u] = fmaf(hv.x, w0, fmaf(hv.y, w1, fmaf(hv.z, w2, fmaf(hv.w, w3, o[u]))));
    }
  }
  float r[FB_];
  #pragma unroll
  for (int u = 0; u < FB_; u++) r[u] = x[u * H_ + t] + o[u];
  __syncthreads();
  #pragma unroll
  for (int u = 0; u < FB_; u++) x[u * H_ + t] = r[u];
  __syncthreads();
  if (t < FB_) {
    float s = 0.f;
    for (int j0 = 0; j0 < H_; j0++) {
      int j = (j0 + t * 2) & (H_ - 1);
      s += x[t * H_ + j];
    }
    float mean = s * (1.f / H_);
    float vs = 0.f;
    for (int j0 = 0; j0 < H_; j0++) {
      int j = (j0 + t * 2) & (H_ - 1);
      float d = x[t * H_ + j] - mean;
      vs = fmaf(d, d, vs);
    }
    mstat[t] = mean;
    istat[t] = rsqrtf(vs * (1.f / H_) + 1e-6f);
  }
  __syncthreads();
  #pragma unroll
  for (int u = 0; u < FB_; u++) {
    float y = (r[u] - mstat[u]) * istat[u];
    y *= mask[n0 + u];
    hV[(size_t)(n0 + u) * H_ + t] = y;
  }
}

// ---------------- output: log_softmax(hV @ W_out + b_out), fp32, 2 nodes/block ----------------
__global__ __launch_bounds__(128) void out_kernel(const float* __restrict__ hV,
    const float* __restrict__ Wout, const float* __restrict__ bout, float* __restrict__ out) {
  int g = threadIdx.x >> 6, t = threadIdx.x & 63;
  int node = blockIdx.x * 2 + g;
  __shared__ float x[2][H_];
  __shared__ float lg[2][V_];
  __shared__ float lse[2];
  x[g][t] = hV[(size_t)node * H_ + t];
  x[g][t + 64] = hV[(size_t)node * H_ + t + 64];
  __syncthreads();
  if (t < V_) {
    float a = bout[t];
    for (int h = 0; h < H_; h++) a = fmaf(x[g][h], Wout[h * V_ + t], a);
    lg[g][t] = a;
  }
  __syncthreads();
  if (t == 0) {
    float mx = -3.4e38f;
    for (int v = 0; v < V_; v++) mx = fmaxf(mx, lg[g][v]);
    float s = 0.f;
    for (int v = 0; v < V_; v++) s += expf(lg[g][v] - mx);
    lse[g] = mx + logf(s);
  }
  __syncthreads();
  if (t < V_) out[(size_t)node * V_ + t] = lg[g][t] - lse[g];
}

// ---------------- host ----------------
extern "C" void kernel_launch(void* const* d_in, const int* in_sizes, int n_in,
                              void* d_out, int out_size, void* d_ws, size_t ws_size,
                              hipStream_t stream) {
  const float* X    = (const float*)d_in[0];
  const float* mask = (const float*)d_in[1];
  const int*   S    = (const int*)d_in[2];
  const float* Wfn  = (const float*)d_in[3];
  const float* bfn  = (const float*)d_in[4];
  const float* Wfe  = (const float*)d_in[5];
  const float* bfe  = (const float*)d_in[6];
  const float* Wv   = (const float*)d_in[7];
  const float* bv   = (const float*)d_in[8];
  const float* We   = (const float*)d_in[9];
  const float* be   = (const float*)d_in[10];
  const float* Ws   = (const float*)d_in[11];
  const float* eWQ  = (const float*)d_in[12];
  const float* eWK  = (const float*)d_in[13];
  const float* eWV  = (const float*)d_in[14];
  const float* eWO  = (const float*)d_in[15];
  const float* eW1  = (const float*)d_in[16];
  const float* eb1  = (const float*)d_in[17];
  const float* eW2  = (const float*)d_in[18];
  const float* eb2  = (const float*)d_in[19];
  const float* dWQ  = (const float*)d_in[20];
  const float* dWK  = (const float*)d_in[21];
  const float* dWV  = (const float*)d_in[22];
  const float* dWO  = (const float*)d_in[23];
  const float* dW1  = (const float*)d_in[24];
  const float* db1  = (const float*)d_in[25];
  const float* dW2  = (const float*)d_in[26];
  const float* db2  = (const float*)d_in[27];
  const float* Wout = (const float*)d_in[28];
  const float* bout = (const float*)d_in[29];
  float* out = (float*)d_out;

  char* w = (char*)d_ws;
  int*    eidx = (int*)w;     w += (size_t)BN_ * K_ * 4;
  float*  dnb  = (float*)w;   w += (size_t)BN_ * K_ * 4;
  float*  vf   = (float*)w;   w += (size_t)BN_ * 6 * 4;
  float*  hVa  = (float*)w;   w += (size_t)BN_ * H_ * 4;
  float*  hVb  = (float*)w;   w += (size_t)BN_ * H_ * 4;
  float*  hVc  = (float*)w;   w += (size_t)BN_ * H_ * 4;
  float*  nKb  = (float*)w;   w += (size_t)BN_ * H_ * 4;
  float*  nVb  = (float*)w;   w += (size_t)BN_ * H_ * 4;
  float*  nKe  = (float*)w;   w += (size_t)BN_ * H_ * 4;
  float*  nVe  = (float*)w;   w += (size_t)BN_ * H_ * 4;
  float*  hE   = (float*)w;   w += (size_t)BN_ * K_ * H_ * 4;

  topk_kernel<<<BN_, 256, 0, stream>>>(X, mask, eidx, dnb);
  dihedral_kernel<<<(BN_ + 255) / 256, 256, 0, stream>>>(X, vf);
  node_embed_kernel<<<BN_, H_, 0, stream>>>(vf, Wfn, bfn, Wv, bv, hVa);
  edge_embed_kernel<<<BN_ * K_ / EB_, H_, 0, stream>>>(eidx, dnb, Wfe, bfe, We, be, hE);

  // encoder: a->b, b->a, a->b
  float* cur = hVa; float* nxt = hVb;
  for (int l = 0; l < 3; l++) {
    const float* WK = eWK + (size_t)l * 2 * H_ * H_;
    const float* WV = eWV + (size_t)l * 2 * H_ * H_;
    node_proj_kernel<<<BN_ / 16, H_, 0, stream>>>(cur,
        WK + (size_t)H_ * H_, WV + (size_t)H_ * H_, nKb, nVb);
    attn_kernel<true><<<BN_, H_, 0, stream>>>(cur, hE, eidx, mask,
        eWQ + (size_t)l * H_ * H_, WK, WV, eWO + (size_t)l * H_ * H_,
        nKb, nVb, nullptr, nullptr, nxt);
    ffn_kernel<<<BN_ / FB_, H_, 0, stream>>>(nxt, mask,
        eW1 + (size_t)l * H_ * 4 * H_, eb1 + (size_t)l * 4 * H_,
        eW2 + (size_t)l * 4 * H_ * H_, eb2 + (size_t)l * H_);
    float* tmp = cur; cur = nxt; nxt = tmp;
  }
  float* henc = cur;  // = hVb
  // decoder: henc->a, a->c, c->a (henc preserved)
  float* din = henc;
  float* douts[3] = { hVa, hVc, hVa };
  for (int l = 0; l < 3; l++) {
    const float* WK = dWK + (size_t)l * 3 * H_ * H_;
    const float* WV = dWV + (size_t)l * 3 * H_ * H_;
    node_proj3_kernel<<<BN_ / 8, H_, 0, stream>>>(S, Ws, din, henc,
        WK + (size_t)H_ * H_, WV + (size_t)H_ * H_,
        WK + (size_t)2 * H_ * H_, WV + (size_t)2 * H_ * H_,
        nKb, nVb, nKe, nVe);
    attn_kernel<false><<<BN_, H_, 0, stream>>>(din, hE, eidx, mask,
        dWQ + (size_t)l * H_ * H_, WK, WV, dWO + (size_t)l * H_ * H_,
        nKb, nVb, nKe, nVe, douts[l]);
    ffn_kernel<<<BN_ / FB_, H_, 0, stream>>>(douts[l], mask,
        dW1 + (size_t)l * H_ * 4 * H_, db1 + (size_t)l * 4 * H_,
        dW2 + (size_t)l * 4 * H_ * H_, db2 + (size_t)l * H_);
    din = douts[l];
  }
  out_kernel<<<BN_ / 2, 128, 0, stream>>>(din, Wout, bout, out);
}